// Round 7
// baseline (120.200 us; speedup 1.0000x reference)
//
#include <hip/hip_runtime.h>
#include <math.h>

#define EMBED 1024
#define NHEAD 8
#define HDIM 128
#define TK 255
#define BATCH 4
#define LQ 128
#define BH 32

typedef __attribute__((ext_vector_type(4))) float f32x4;
typedef __attribute__((ext_vector_type(8))) short short8;
typedef __attribute__((ext_vector_type(4))) short short4v;

static __device__ __forceinline__ unsigned short f2bf(float f) {
    unsigned u = __float_as_uint(f);
    u += 0x7FFFu + ((u >> 16) & 1u);
    return (unsigned short)(u >> 16);
}
static __device__ __forceinline__ float bfbits2f(unsigned short s) {
    return __uint_as_float(((unsigned)s) << 16);
}

// ============ pack: fp32 [rows][1024] -> bf16 [rows][2048] = [hi | lo] ============
__global__ __launch_bounds__(256) void pack_all(
    const float* __restrict__ query, const float* __restrict__ key_t,
    const float* __restrict__ value, const float* __restrict__ ipw,
    const float* __restrict__ opw,
    unsigned short* __restrict__ apk, unsigned short* __restrict__ wpk)
{
    const int APKC = 2560 * 256;
    const int TOT = APKC + 4096 * 256;
    for (int idx = blockIdx.x * 256 + threadIdx.x; idx < TOT; idx += gridDim.x * 256) {
        const bool isA = idx < APKC;
        const int rel = isA ? idx : idx - APKC;
        const int row = rel >> 8, c4 = rel & 255;
        const float* src = nullptr; long srow = 0;
        unsigned short* dst;
        if (isA) {
            dst = apk + (long)row * 2048;
            if (row < 512) { src = query; srow = row; }
            else if (row < 1536) { if (row - 512 < 1020) { src = key_t; srow = row - 512; } }
            else { if (row - 1536 < 1020) { src = value; srow = row - 1536; } }
        } else {
            dst = wpk + (long)row * 2048;
            if (row < 3072) { src = ipw; srow = row; }
            else { src = opw; srow = row - 3072; }
        }
        float4 f = make_float4(0.f, 0.f, 0.f, 0.f);
        if (src) f = *(const float4*)(src + srow * 1024 + c4 * 4);
        const unsigned short h0 = f2bf(f.x), h1 = f2bf(f.y), h2 = f2bf(f.z), h3 = f2bf(f.w);
        short4v hv, lv;
        hv[0] = (short)h0; hv[1] = (short)h1; hv[2] = (short)h2; hv[3] = (short)h3;
        lv[0] = (short)f2bf(f.x - bfbits2f(h0));
        lv[1] = (short)f2bf(f.y - bfbits2f(h1));
        lv[2] = (short)f2bf(f.z - bfbits2f(h2));
        lv[3] = (short)f2bf(f.w - bfbits2f(h3));
        *(short4v*)(dst + c4 * 4) = hv;
        *(short4v*)(dst + 1024 + c4 * 4) = lv;
    }
}

// ============ packed bf16 GEMM; nkb k-blocks of 128 walking split terms ============
// nkb=24: hi.hi, lo.hi, hi.lo (3-term). nkb=16: hi.hi, lo.hi (2-term).
template<int BM, int BN>
__device__ __forceinline__ void bgemm(
    const unsigned short* __restrict__ A,
    const unsigned short* __restrict__ B,
    const float* __restrict__ bias,
    float* __restrict__ C, long ldc, float scale,
    int m0, int n0, int nkb, unsigned char* lds)
{
    constexpr int AOF = 0, BOF = BM * 256;
    constexpr int FM = BM / 64, FN = BN / 64;   // fragments per wave (wave tile BM/2 x BN/2)
    constexpr int FM2 = BM / 32, FN2 = BN / 32;
    constexpr int CA = BM / 16, CB = BN / 16;
    const int t = threadIdx.x, lane = t & 63, wave = t >> 6;
    const int wm = wave >> 1, wn = wave & 1;

    f32x4 acc[FM2][FN2];
    #pragma unroll
    for (int i = 0; i < FM2; ++i)
        #pragma unroll
        for (int j = 0; j < FN2; ++j)
            #pragma unroll
            for (int e = 0; e < 4; ++e) acc[i][j][e] = 0.f;

    short8 ra[CA], rb[CB];
    #pragma unroll
    for (int c = 0; c < CA; ++c) {
        const int fi = c * 256 + t, row = fi >> 4, u = fi & 15;
        ra[c] = *(const short8*)(A + (long)(m0 + row) * 2048 + u * 8);
    }
    #pragma unroll
    for (int c = 0; c < CB; ++c) {
        const int fi = c * 256 + t, row = fi >> 4, u = fi & 15;
        rb[c] = *(const short8*)(B + (long)(n0 + row) * 2048 + u * 8);
    }

    for (int kt = 0; kt < nkb; ++kt) {
        #pragma unroll
        for (int c = 0; c < CA; ++c) {
            const int fi = c * 256 + t, row = fi >> 4, u = fi & 15;
            *(short8*)(lds + AOF + row * 256 + ((u ^ (row & 15)) << 4)) = ra[c];
        }
        #pragma unroll
        for (int c = 0; c < CB; ++c) {
            const int fi = c * 256 + t, row = fi >> 4, u = fi & 15;
            *(short8*)(lds + BOF + row * 256 + ((u ^ (row & 15)) << 4)) = rb[c];
        }
        __syncthreads();
        if (kt + 1 < nkb) {
            const int kn = kt + 1;
            const int anext = (kn & 15) << 7;                          // hi(8) lo(8) hi(8)
            const int bnext = ((kn & 7) << 7) + (kn >= 16 ? 1024 : 0); // hi hi lo
            #pragma unroll
            for (int c = 0; c < CA; ++c) {
                const int fi = c * 256 + t, row = fi >> 4, u = fi & 15;
                ra[c] = *(const short8*)(A + (long)(m0 + row) * 2048 + anext + u * 8);
            }
            #pragma unroll
            for (int c = 0; c < CB; ++c) {
                const int fi = c * 256 + t, row = fi >> 4, u = fi & 15;
                rb[c] = *(const short8*)(B + (long)(n0 + row) * 2048 + bnext + u * 8);
            }
        }
        #pragma unroll
        for (int ks = 0; ks < 4; ++ks) {
            short8 af[FM2], bg[FN2];
            #pragma unroll
            for (int fm = 0; fm < FM2; ++fm) {
                const int row = wm * (BM / 2) + fm * 16 + (lane & 15);
                const int u = (ks * 4 + (lane >> 4)) ^ (row & 15);
                af[fm] = *(const short8*)(lds + AOF + row * 256 + (u << 4));
            }
            #pragma unroll
            for (int fn = 0; fn < FN2; ++fn) {
                const int row = wn * (BN / 2) + fn * 16 + (lane & 15);
                const int u = (ks * 4 + (lane >> 4)) ^ (row & 15);
                bg[fn] = *(const short8*)(lds + BOF + row * 256 + (u << 4));
            }
            #pragma unroll
            for (int fm = 0; fm < FM2; ++fm)
                #pragma unroll
                for (int fn = 0; fn < FN2; ++fn)
                    acc[fm][fn] = __builtin_amdgcn_mfma_f32_16x16x32_bf16(af[fm], bg[fn], acc[fm][fn], 0, 0, 0);
        }
        __syncthreads();
    }

    #pragma unroll
    for (int fm = 0; fm < FM2; ++fm)
        #pragma unroll
        for (int i = 0; i < 4; ++i) {
            const int m = m0 + wm * (BM / 2) + fm * 16 + ((lane >> 4) << 2) + i;
            #pragma unroll
            for (int fn = 0; fn < FN2; ++fn) {
                const int n = n0 + wn * (BN / 2) + fn * 16 + (lane & 15);
                float v = acc[fm][fn][i];
                if (bias) v += bias[n];
                C[(long)m * ldc + n] = v * scale;
            }
        }
}

// ---- fused q/k/v projections, 128x128 tiles. grid (8, 20)
__global__ __launch_bounds__(256) void qkvb_kernel(
    const unsigned short* __restrict__ apk, const unsigned short* __restrict__ wpk,
    const float* __restrict__ ipb,
    float* __restrict__ qp, float* __restrict__ kp, float* __restrict__ vp, float qscale)
{
    __shared__ __align__(16) unsigned char lds[(128 + 128) * 256];
    const int y = blockIdx.y;
    const unsigned short* A; const unsigned short* B; const float* bias; float* C;
    float scale; int m0; int nkb;
    if (y < 4)       { A = apk;                m0 = y * 128;        B = wpk;                bias = ipb;        C = qp; scale = qscale; nkb = 24; }
    else if (y < 12) { A = apk + 512L * 2048;  m0 = (y - 4) * 128;  B = wpk + 1024L * 2048; bias = ipb + 1024; C = kp; scale = 1.f;    nkb = 24; }
    else             { A = apk + 1536L * 2048; m0 = (y - 12) * 128; B = wpk + 2048L * 2048; bias = ipb + 2048; C = vp; scale = 1.f;    nkb = 16; }
    bgemm<128, 128>(A, B, bias, C, 1024, scale, m0, blockIdx.x * 128, nkb, lds);
}

// ---- out projection, 64x64 tiles. grid (16, 8)
__global__ __launch_bounds__(256) void outprojb_kernel(
    const unsigned short* __restrict__ apk2, const unsigned short* __restrict__ wpk,
    const float* __restrict__ opb, float* __restrict__ out)
{
    __shared__ __align__(16) unsigned char lds[(64 + 64) * 256];
    bgemm<64, 64>(apk2, wpk + 3072L * 2048, opb, out, 1024, 1.f,
                  blockIdx.y * 64, blockIdx.x * 64, 16, lds);
}

// ============ ksuffix: sbuf[b][n][e] = sum_{m=n..254} kp[(m*4+b)][e], sbuf[b][255][e]=0 ====
__global__ __launch_bounds__(256) void ksuffix_kernel(
    const float* __restrict__ kp, float* __restrict__ sbuf)
{
    const int b = blockIdx.y;
    const int cl = threadIdx.x & 31;
    const int e = blockIdx.x * 32 + cl;
    const int seg = threadIdx.x >> 5;       // 0..7
    __shared__ float tot[8][33];
    float acc = 0.f;
    const int nhi = seg * 32 + 31;
    #pragma unroll 8
    for (int i = 0; i < 32; ++i) {
        const int n = nhi - i;
        float v = 0.f;
        if (n < TK) v = kp[(long)(n * 4 + b) * 1024 + e];
        acc += v;
        sbuf[((long)b * 256 + n) * 1024 + e] = acc;
    }
    tot[seg][cl] = acc;
    __syncthreads();
    float add = 0.f;
    #pragma unroll
    for (int s = 0; s < 8; ++s) if (s > seg) add += tot[s][cl];
    if (seg < 7) {
        #pragma unroll 8
        for (int i = 0; i < 32; ++i) {
            const int n = seg * 32 + i;
            sbuf[((long)b * 256 + n) * 1024 + e] += add;
        }
    }
}

// ============ fused attention, 4-way q split: per (b,h,qq) 32 q-rows. grid 128 ====
// LDS: QH 8K | QL 8K | KH 16K (Vt overlay) | KL 16K | PH 16K | PL 16K | RED 512B | INV 128B
#define F_QH 0
#define F_QL 8192
#define F_KH 16384
#define F_KL 32768
#define F_PH 49152
#define F_PL 65536
#define F_RED 81920
#define F_INV 82432

__global__ __launch_bounds__(256, 1) void fused_attn_kernel(
    const float* __restrict__ qp, const float* __restrict__ sbuf,
    const float* __restrict__ vp, const int* __restrict__ indices,
    unsigned short* __restrict__ apk2)
{
    __shared__ __align__(16) unsigned char lds[82560];
    __shared__ int onode[256];
    const int blk = blockIdx.x;
    const int qq = blk & 3, bh = blk >> 2, b = bh >> 3, h = bh & 7;
    const int t = threadIdx.x, lane = t & 63, wave = t >> 6;
    const int wm = wave >> 1, wn = wave & 1;
    float* red = (float*)(lds + F_RED);   // [2 phase][2 wn][32 row]
    float* inv = (float*)(lds + F_INV);   // [32]

    // ---- onode table: end-of-subtree + 1 (preorder contiguity)
    if (t < TK) {
        const int r0 = indices[(b * TK + t) * 2 + 0];
        const int c0 = indices[(b * TK + t) * 2 + 1];
        onode[t] = t + 2 * (c0 - r0) + 1;
    } else if (t < 256) {
        onode[t] = 255;   // k~ = S255 - S255 = 0
    }

    // ---- stage Q (32 rows x 128 cols) -> hi/lo, pitch 256B, unit ^= row&15
    {
        const int c4 = t & 31, r8 = t >> 5;
        #pragma unroll
        for (int rr = 0; rr < 4; ++rr) {
            const int row = r8 + rr * 8;
            const int tq = qq * 32 + row;
            float4 f = *(const float4*)(qp + (long)(tq * 4 + b) * 1024 + h * 128 + c4 * 4);
            const unsigned short h0 = f2bf(f.x), h1 = f2bf(f.y), h2 = f2bf(f.z), h3 = f2bf(f.w);
            short4v hv, lv;
            hv[0] = (short)h0; hv[1] = (short)h1; hv[2] = (short)h2; hv[3] = (short)h3;
            lv[0] = (short)f2bf(f.x - bfbits2f(h0));
            lv[1] = (short)f2bf(f.y - bfbits2f(h1));
            lv[2] = (short)f2bf(f.z - bfbits2f(h2));
            lv[3] = (short)f2bf(f.w - bfbits2f(h3));
            const int byte = row * 256 + ((((c4 >> 1) ^ (row & 15)) << 4) | ((c4 & 1) << 3));
            *(short4v*)(lds + F_QH + byte) = hv;
            *(short4v*)(lds + F_QL + byte) = lv;
        }
    }

    // ---- QK^T: acc[nb][fn], 3-term; per-wave rows wm*16, cols wn*32+fn*16
    f32x4 acc[4][2];
    #pragma unroll
    for (int nb = 0; nb < 4; ++nb)
        #pragma unroll
        for (int j = 0; j < 2; ++j)
            #pragma unroll
            for (int e = 0; e < 4; ++e) acc[nb][j][e] = 0.f;

    #pragma unroll
    for (int nb = 0; nb < 4; ++nb) {
        __syncthreads();
        {   // stage k~ block: k~_node = S[node] - S[onode[node]]
            const int c4 = t & 31, r8 = t >> 5;
            const float* sb = sbuf + (long)b * 256 * 1024 + h * 128 + c4 * 4;
            #pragma unroll
            for (int rr = 0; rr < 8; ++rr) {
                const int nl = r8 + rr * 8;
                const int node = nb * 64 + nl;
                float4 f0 = *(const float4*)(sb + (long)node * 1024);
                float4 f1 = *(const float4*)(sb + (long)onode[node] * 1024);
                float4 f = make_float4(f0.x - f1.x, f0.y - f1.y, f0.z - f1.z, f0.w - f1.w);
                const unsigned short h0 = f2bf(f.x), h1 = f2bf(f.y), h2 = f2bf(f.z), h3 = f2bf(f.w);
                short4v hv, lv;
                hv[0] = (short)h0; hv[1] = (short)h1; hv[2] = (short)h2; hv[3] = (short)h3;
                lv[0] = (short)f2bf(f.x - bfbits2f(h0));
                lv[1] = (short)f2bf(f.y - bfbits2f(h1));
                lv[2] = (short)f2bf(f.z - bfbits2f(h2));
                lv[3] = (short)f2bf(f.w - bfbits2f(h3));
                const int byte = nl * 256 + ((((c4 >> 1) ^ (nl & 15)) << 4) | ((c4 & 1) << 3));
                *(short4v*)(lds + F_KH + byte) = hv;
                *(short4v*)(lds + F_KL + byte) = lv;
            }
        }
        __syncthreads();
        #pragma unroll
        for (int ks = 0; ks < 4; ++ks) {
            short8 ah, al, bh_[2], bl[2];
            {
                const int row = wm * 16 + (lane & 15);
                const int byte = row * 256 + (((ks * 4 + (lane >> 4)) ^ (row & 15)) << 4);
                ah = *(const short8*)(lds + F_QH + byte);
                al = *(const short8*)(lds + F_QL + byte);
            }
            #pragma unroll
            for (int fn = 0; fn < 2; ++fn) {
                const int row = wn * 32 + fn * 16 + (lane & 15);
                const int byte = row * 256 + (((ks * 4 + (lane >> 4)) ^ (row & 15)) << 4);
                bh_[fn] = *(const short8*)(lds + F_KH + byte);
                bl[fn] = *(const short8*)(lds + F_KL + byte);
            }
            #pragma unroll
            for (int fn = 0; fn < 2; ++fn) {
                acc[nb][fn] = __builtin_amdgcn_mfma_f32_16x16x32_bf16(ah, bh_[fn], acc[nb][fn], 0, 0, 0);
                acc[nb][fn] = __builtin_amdgcn_mfma_f32_16x16x32_bf16(al, bh_[fn], acc[nb][fn], 0, 0, 0);
                acc[nb][fn] = __builtin_amdgcn_mfma_f32_16x16x32_bf16(ah, bl[fn], acc[nb][fn], 0, 0, 0);
            }
        }
    }

    // ---- softmax over 256 cols (col>=255 masked)
    float pmax[4] = {-1e30f, -1e30f, -1e30f, -1e30f};
    #pragma unroll
    for (int nb = 0; nb < 4; ++nb)
        #pragma unroll
        for (int fn = 0; fn < 2; ++fn)
            #pragma unroll
            for (int i = 0; i < 4; ++i) {
                const int col = nb * 64 + wn * 32 + fn * 16 + (lane & 15);
                const float s = (col < TK) ? acc[nb][fn][i] : -1e30f;
                pmax[i] = fmaxf(pmax[i], s);
            }
    #pragma unroll
    for (int off = 1; off < 16; off <<= 1)
        #pragma unroll
        for (int i = 0; i < 4; ++i) pmax[i] = fmaxf(pmax[i], __shfl_xor(pmax[i], off));
    if ((lane & 15) == 0) {
        #pragma unroll
        for (int i = 0; i < 4; ++i) {
            const int row = wm * 16 + ((lane >> 4) << 2) + i;
            red[wn * 32 + row] = pmax[i];
        }
    }
    __syncthreads();
    float rm[4];
    #pragma unroll
    for (int i = 0; i < 4; ++i) {
        const int row = wm * 16 + ((lane >> 4) << 2) + i;
        rm[i] = fmaxf(red[row], red[32 + row]);
    }
    float psum[4] = {0.f, 0.f, 0.f, 0.f};
    #pragma unroll
    for (int nb = 0; nb < 4; ++nb)
        #pragma unroll
        for (int fn = 0; fn < 2; ++fn)
            #pragma unroll
            for (int i = 0; i < 4; ++i) {
                const int col = nb * 64 + wn * 32 + fn * 16 + (lane & 15);
                const int row = wm * 16 + ((lane >> 4) << 2) + i;
                float p = 0.f;
                if (col < TK) p = __expf(acc[nb][fn][i] - rm[i]);
                psum[i] += p;
                const unsigned short hp = f2bf(p);
                const unsigned short lp = f2bf(p - bfbits2f(hp));
                const int u = ((col >> 3) ^ ((row & 15) << 1));
                const int byte = row * 512 + (u << 4) + (col & 7) * 2;
                *(unsigned short*)(lds + F_PH + byte) = hp;
                *(unsigned short*)(lds + F_PL + byte) = lp;
            }
    #pragma unroll
    for (int off = 1; off < 16; off <<= 1)
        #pragma unroll
        for (int i = 0; i < 4; ++i) psum[i] += __shfl_xor(psum[i], off);
    if ((lane & 15) == 0) {
        #pragma unroll
        for (int i = 0; i < 4; ++i) {
            const int row = wm * 16 + ((lane >> 4) << 2) + i;
            red[64 + wn * 32 + row] = psum[i];
        }
    }
    __syncthreads();
    if (wn == 0 && (lane & 15) == 0) {
        #pragma unroll
        for (int i = 0; i < 4; ++i) {
            const int row = wm * 16 + ((lane >> 4) << 2) + i;
            inv[row] = 1.f / (red[64 + row] + red[96 + row]);
        }
    }

    // ---- PV: O = P . V, 2-term (P hi+lo, V hi). Vt staged [128 d][64 n] in KH region.
    f32x4 accO[4];
    #pragma unroll
    for (int fn = 0; fn < 4; ++fn)
        #pragma unroll
        for (int e = 0; e < 4; ++e) accO[fn][e] = 0.f;

    #pragma unroll
    for (int nb = 0; nb < 4; ++nb) {
        __syncthreads();
        {   // transpose-stage V hi: Vt[d][n], pitch 128B, unit ^= d&7
            const int c4 = t & 31, r8 = t >> 5;
            #pragma unroll
            for (int rr = 0; rr < 8; ++rr) {
                const int nl = r8 + rr * 8;
                const int node = nb * 64 + nl;
                float4 f = make_float4(0.f, 0.f, 0.f, 0.f);
                if (node < TK) f = *(const float4*)(vp + (long)(node * 4 + b) * 1024 + h * 128 + c4 * 4);
                const float fa[4] = {f.x, f.y, f.z, f.w};
                #pragma unroll
                for (int j = 0; j < 4; ++j) {
                    const int d = c4 * 4 + j;
                    const int byte = d * 128 + ((((nl >> 3) ^ (d & 7)) << 4) | ((nl & 7) << 1));
                    *(unsigned short*)(lds + F_KH + byte) = f2bf(fa[j]);
                }
            }
        }
        __syncthreads();
        #pragma unroll
        for (int ks = 0; ks < 2; ++ks) {
            short8 pa, pl, vb[4];
            {
                const int row = wm * 16 + (lane & 15);
                const int u = (nb * 8 + ks * 4 + (lane >> 4)) ^ ((row & 15) << 1);
                const int byte = row * 512 + (u << 4);
                pa = *(const short8*)(lds + F_PH + byte);
                pl = *(const short8*)(lds + F_PL + byte);
            }
            #pragma unroll
            for (int fn = 0; fn < 4; ++fn) {
                const int d = wn * 64 + fn * 16 + (lane & 15);
                const int u = (ks * 4 + (lane >> 4)) ^ (d & 7);
                const int byte = d * 128 + (u << 4);
                vb[fn] = *(const short8*)(lds + F_KH + byte);
            }
            #pragma unroll
            for (int fn = 0; fn < 4; ++fn) {
                accO[fn] = __builtin_amdgcn_mfma_f32_16x16x32_bf16(pa, vb[fn], accO[fn], 0, 0, 0);
                accO[fn] = __builtin_amdgcn_mfma_f32_16x16x32_bf16(pl, vb[fn], accO[fn], 0, 0, 0);
            }
        }
    }

    // ---- epilogue: normalize + write packed bf16 [hi|lo] attn rows directly
    __syncthreads();
    #pragma unroll
    for (int i = 0; i < 4; ++i) {
        const int row = wm * 16 + ((lane >> 4) << 2) + i;
        const float iv = inv[row];
        const int arow = (qq * 32 + row) * 4 + b;
        #pragma unroll
        for (int fn = 0; fn < 4; ++fn) {
            const int col = h * 128 + wn * 64 + fn * 16 + (lane & 15);
            const float val = accO[fn][i] * iv;
            const unsigned short hv = f2bf(val);
            const unsigned short lv = f2bf(val - bfbits2f(hv));
            apk2[(long)arow * 2048 + col] = hv;
            apk2[(long)arow * 2048 + 1024 + col] = lv;
        }
    }
}

extern "C" void kernel_launch(void* const* d_in, const int* in_sizes, int n_in,
                              void* d_out, int out_size, void* d_ws, size_t ws_size,
                              hipStream_t stream) {
    const float* query   = (const float*)d_in[0];
    const float* key_t   = (const float*)d_in[1];
    const float* value   = (const float*)d_in[2];
    const int*   indices = (const int*)d_in[3];
    const float* ipw     = (const float*)d_in[4];
    const float* ipb     = (const float*)d_in[5];
    const float* opw     = (const float*)d_in[6];
    const float* opb     = (const float*)d_in[7];
    float* out = (float*)d_out;

    float* ws = (float*)d_ws;
    float* kp   = ws;                        // [1024][1024]
    float* vp   = kp + 1048576;              // [1024][1024]
    float* qp   = vp + 1048576;              // [512][1024]
    float* sbuf = qp + 524288;               // [4][256][1024] suffix sums
    unsigned short* apk  = (unsigned short*)(sbuf + 1048576);  // [2560][2048]
    unsigned short* wpk  = apk + 2560L * 2048;                 // [4096][2048]
    unsigned short* apk2 = apk;              // overlay (apk dead after qkvb)

    const float qscale = 0.08838834764831843f;  // 128^-0.5

    pack_all<<<dim3(2048), 256, 0, stream>>>(query, key_t, value, ipw, opw, apk, wpk);

    qkvb_kernel<<<dim3(8, 20), 256, 0, stream>>>(apk, wpk, ipb, qp, kp, vp, qscale);

    ksuffix_kernel<<<dim3(32, 4), 256, 0, stream>>>(kp, sbuf);

    fused_attn_kernel<<<dim3(128), 256, 0, stream>>>(qp, sbuf, vp, indices, apk2);

    outprojb_kernel<<<dim3(16, 8), 256, 0, stream>>>(apk2, wpk, opb, out);
}

// Round 8
// 94.593 us; speedup vs baseline: 1.2707x; 1.2707x over previous
//
#include <hip/hip_runtime.h>
#include <math.h>

#define EMBED 1024
#define NHEAD 8
#define HDIM 128
#define TK 255
#define BATCH 4
#define LQ 128
#define BH 32

typedef __attribute__((ext_vector_type(4))) float f32x4;
typedef __attribute__((ext_vector_type(8))) short short8;
typedef __attribute__((ext_vector_type(4))) short short4v;

static __device__ __forceinline__ unsigned short f2bf(float f) {
    unsigned u = __float_as_uint(f);
    u += 0x7FFFu + ((u >> 16) & 1u);
    return (unsigned short)(u >> 16);
}
static __device__ __forceinline__ float bfbits2f(unsigned short s) {
    return __uint_as_float(((unsigned)s) << 16);
}

// ============ pack: fp32 [rows][1024] -> bf16 [rows][2048] = [hi | lo] ============
__global__ __launch_bounds__(256) void pack_all(
    const float* __restrict__ query, const float* __restrict__ key_t,
    const float* __restrict__ value, const float* __restrict__ ipw,
    const float* __restrict__ opw,
    unsigned short* __restrict__ apk, unsigned short* __restrict__ wpk)
{
    const int APKC = 2560 * 256;
    const int TOT = APKC + 4096 * 256;
    for (int idx = blockIdx.x * 256 + threadIdx.x; idx < TOT; idx += gridDim.x * 256) {
        const bool isA = idx < APKC;
        const int rel = isA ? idx : idx - APKC;
        const int row = rel >> 8, c4 = rel & 255;
        const float* src = nullptr; long srow = 0;
        unsigned short* dst;
        if (isA) {
            dst = apk + (long)row * 2048;
            if (row < 512) { src = query; srow = row; }
            else if (row < 1536) { if (row - 512 < 1020) { src = key_t; srow = row - 512; } }
            else { if (row - 1536 < 1020) { src = value; srow = row - 1536; } }
        } else {
            dst = wpk + (long)row * 2048;
            if (row < 3072) { src = ipw; srow = row; }
            else { src = opw; srow = row - 3072; }
        }
        float4 f = make_float4(0.f, 0.f, 0.f, 0.f);
        if (src) f = *(const float4*)(src + srow * 1024 + c4 * 4);
        const unsigned short h0 = f2bf(f.x), h1 = f2bf(f.y), h2 = f2bf(f.z), h3 = f2bf(f.w);
        short4v hv, lv;
        hv[0] = (short)h0; hv[1] = (short)h1; hv[2] = (short)h2; hv[3] = (short)h3;
        lv[0] = (short)f2bf(f.x - bfbits2f(h0));
        lv[1] = (short)f2bf(f.y - bfbits2f(h1));
        lv[2] = (short)f2bf(f.z - bfbits2f(h2));
        lv[3] = (short)f2bf(f.w - bfbits2f(h3));
        *(short4v*)(dst + c4 * 4) = hv;
        *(short4v*)(dst + 1024 + c4 * 4) = lv;
    }
}

// ============ bgemm2: all-plane BK=64 staging, TERMS MFMAs per fragment pair ============
// A,B: bf16 [rows][2048] = [hi|lo]. LDS planes: A_hi, A_lo, B_hi (, B_lo if TERMS==3),
// each [rows][64] bf16, 128B pitch, 16B-unit XOR swizzle u ^= row&7.
// C = (A.B^T + bias) * scale; terms: hh + lh (+ hl).
template<int BM, int BN, int TERMS>
__device__ __forceinline__ void bgemm2(
    const unsigned short* __restrict__ A,
    const unsigned short* __restrict__ B,
    const float* __restrict__ bias,
    float* __restrict__ C, long ldc, float scale,
    int m0, int n0, unsigned char* lds)
{
    constexpr int AH = 0;
    constexpr int AL = BM * 128;
    constexpr int BHo = 2 * BM * 128;
    constexpr int BLo = BHo + BN * 128;
    constexpr int FM2 = BM / 32, FN2 = BN / 32;
    constexpr int CA = BM / 32;       // staging passes per plane (256 thr x 16B = 32 rows)
    constexpr int CB = BN / 32;
    const int t = threadIdx.x, lane = t & 63, wave = t >> 6;
    const int wm = wave >> 1, wn = wave & 1;

    f32x4 acc[FM2][FN2];
    #pragma unroll
    for (int i = 0; i < FM2; ++i)
        #pragma unroll
        for (int j = 0; j < FN2; ++j)
            #pragma unroll
            for (int e = 0; e < 4; ++e) acc[i][j][e] = 0.f;

    const int srow_a = t >> 3, su = t & 7;      // staging row-in-pass / 16B-unit
    short8 rah[CA], ral[CA], rbh[CB], rbl[CB];

    // prefetch kt = 0
    #pragma unroll
    for (int c = 0; c < CA; ++c) {
        const long base = (long)(m0 + c * 32 + srow_a) * 2048 + su * 8;
        rah[c] = *(const short8*)(A + base);
        ral[c] = *(const short8*)(A + base + 1024);
    }
    #pragma unroll
    for (int c = 0; c < CB; ++c) {
        const long base = (long)(n0 + c * 32 + srow_a) * 2048 + su * 8;
        rbh[c] = *(const short8*)(B + base);
        if (TERMS == 3) rbl[c] = *(const short8*)(B + base + 1024);
    }

    for (int kt = 0; kt < 16; ++kt) {
        #pragma unroll
        for (int c = 0; c < CA; ++c) {
            const int row = c * 32 + srow_a;
            const int byte = row * 128 + ((su ^ (row & 7)) << 4);
            *(short8*)(lds + AH + byte) = rah[c];
            *(short8*)(lds + AL + byte) = ral[c];
        }
        #pragma unroll
        for (int c = 0; c < CB; ++c) {
            const int row = c * 32 + srow_a;
            const int byte = row * 128 + ((su ^ (row & 7)) << 4);
            *(short8*)(lds + BHo + byte) = rbh[c];
            if (TERMS == 3) *(short8*)(lds + BLo + byte) = rbl[c];
        }
        __syncthreads();
        if (kt + 1 < 16) {
            const int off = (kt + 1) * 64;
            #pragma unroll
            for (int c = 0; c < CA; ++c) {
                const long base = (long)(m0 + c * 32 + srow_a) * 2048 + off + su * 8;
                rah[c] = *(const short8*)(A + base);
                ral[c] = *(const short8*)(A + base + 1024);
            }
            #pragma unroll
            for (int c = 0; c < CB; ++c) {
                const long base = (long)(n0 + c * 32 + srow_a) * 2048 + off + su * 8;
                rbh[c] = *(const short8*)(B + base);
                if (TERMS == 3) rbl[c] = *(const short8*)(B + base + 1024);
            }
        }
        #pragma unroll
        for (int ks = 0; ks < 2; ++ks) {
            short8 afh[FM2], afl[FM2], bgh[FN2], bgl[FN2];
            #pragma unroll
            for (int fm = 0; fm < FM2; ++fm) {
                const int row = wm * (BM / 2) + fm * 16 + (lane & 15);
                const int byte = row * 128 + (((ks * 4 + (lane >> 4)) ^ (row & 7)) << 4);
                afh[fm] = *(const short8*)(lds + AH + byte);
                afl[fm] = *(const short8*)(lds + AL + byte);
            }
            #pragma unroll
            for (int fn = 0; fn < FN2; ++fn) {
                const int row = wn * (BN / 2) + fn * 16 + (lane & 15);
                const int byte = row * 128 + (((ks * 4 + (lane >> 4)) ^ (row & 7)) << 4);
                bgh[fn] = *(const short8*)(lds + BHo + byte);
                if (TERMS == 3) bgl[fn] = *(const short8*)(lds + BLo + byte);
            }
            #pragma unroll
            for (int fm = 0; fm < FM2; ++fm)
                #pragma unroll
                for (int fn = 0; fn < FN2; ++fn) {
                    acc[fm][fn] = __builtin_amdgcn_mfma_f32_16x16x32_bf16(afh[fm], bgh[fn], acc[fm][fn], 0, 0, 0);
                    acc[fm][fn] = __builtin_amdgcn_mfma_f32_16x16x32_bf16(afl[fm], bgh[fn], acc[fm][fn], 0, 0, 0);
                    if (TERMS == 3)
                        acc[fm][fn] = __builtin_amdgcn_mfma_f32_16x16x32_bf16(afh[fm], bgl[fn], acc[fm][fn], 0, 0, 0);
                }
        }
        __syncthreads();
    }

    #pragma unroll
    for (int fm = 0; fm < FM2; ++fm)
        #pragma unroll
        for (int i = 0; i < 4; ++i) {
            const int m = m0 + wm * (BM / 2) + fm * 16 + ((lane >> 4) << 2) + i;
            #pragma unroll
            for (int fn = 0; fn < FN2; ++fn) {
                const int n = n0 + wn * (BN / 2) + fn * 16 + (lane & 15);
                float v = acc[fm][fn][i];
                if (bias) v += bias[n];
                C[(long)m * ldc + n] = v * scale;
            }
        }
}

// ---- fused q/k/v projections, 64x64 tiles. grid (16, 40)
__global__ __launch_bounds__(256) void qkvb_kernel(
    const unsigned short* __restrict__ apk, const unsigned short* __restrict__ wpk,
    const float* __restrict__ ipb,
    float* __restrict__ qp, float* __restrict__ kp, float* __restrict__ vp, float qscale)
{
    __shared__ __align__(16) unsigned char lds[4 * 64 * 128];
    const int y = blockIdx.y;
    if (y < 8) {
        bgemm2<64, 64, 3>(apk, wpk, ipb, qp, 1024, qscale,
                          y * 64, blockIdx.x * 64, lds);
    } else if (y < 24) {
        bgemm2<64, 64, 3>(apk + 512L * 2048, wpk + 1024L * 2048, ipb + 1024, kp, 1024, 1.f,
                          (y - 8) * 64, blockIdx.x * 64, lds);
    } else {
        bgemm2<64, 64, 2>(apk + 1536L * 2048, wpk + 2048L * 2048, ipb + 2048, vp, 1024, 1.f,
                          (y - 24) * 64, blockIdx.x * 64, lds);
    }
}

// ---- out projection, 64x64 tiles, 2-term. grid (16, 8)
__global__ __launch_bounds__(256) void outprojb_kernel(
    const unsigned short* __restrict__ apk2, const unsigned short* __restrict__ wpk,
    const float* __restrict__ opb, float* __restrict__ out)
{
    __shared__ __align__(16) unsigned char lds[3 * 64 * 128];
    bgemm2<64, 64, 2>(apk2, wpk + 3072L * 2048, opb, out, 1024, 1.f,
                      blockIdx.y * 64, blockIdx.x * 64, lds);
}

// ============ ksuffix: sbuf[b][n][e] = sum_{m=n..254} kp[(m*4+b)][e], sbuf[b][255][e]=0 ====
__global__ __launch_bounds__(256) void ksuffix_kernel(
    const float* __restrict__ kp, float* __restrict__ sbuf)
{
    const int b = blockIdx.y;
    const int cl = threadIdx.x & 31;
    const int e = blockIdx.x * 32 + cl;
    const int seg = threadIdx.x >> 5;       // 0..7
    __shared__ float tot[8][33];
    float acc = 0.f;
    const int nhi = seg * 32 + 31;
    #pragma unroll 8
    for (int i = 0; i < 32; ++i) {
        const int n = nhi - i;
        float v = 0.f;
        if (n < TK) v = kp[(long)(n * 4 + b) * 1024 + e];
        acc += v;
        sbuf[((long)b * 256 + n) * 1024 + e] = acc;
    }
    tot[seg][cl] = acc;
    __syncthreads();
    float add = 0.f;
    #pragma unroll
    for (int s = 0; s < 8; ++s) if (s > seg) add += tot[s][cl];
    if (seg < 7) {
        #pragma unroll 8
        for (int i = 0; i < 32; ++i) {
            const int n = seg * 32 + i;
            sbuf[((long)b * 256 + n) * 1024 + e] += add;
        }
    }
}

// ============ fused attention, 4-way q split: per (b,h,qq) 32 q-rows. grid 128 ====
// LDS: QH 8K | QL 8K | KH 16K (Vt overlay) | KL 16K | PH 16K | PL 16K | RED 512B | INV 128B
#define F_QH 0
#define F_QL 8192
#define F_KH 16384
#define F_KL 32768
#define F_PH 49152
#define F_PL 65536
#define F_RED 81920
#define F_INV 82432

__global__ __launch_bounds__(256, 1) void fused_attn_kernel(
    const float* __restrict__ qp, const float* __restrict__ sbuf,
    const float* __restrict__ vp, const int* __restrict__ indices,
    unsigned short* __restrict__ apk2)
{
    __shared__ __align__(16) unsigned char lds[82560];
    __shared__ int onode[256];
    const int blk = blockIdx.x;
    const int qq = blk & 3, bh = blk >> 2, b = bh >> 3, h = bh & 7;
    const int t = threadIdx.x, lane = t & 63, wave = t >> 6;
    const int wm = wave >> 1, wn = wave & 1;
    float* red = (float*)(lds + F_RED);
    float* inv = (float*)(lds + F_INV);

    if (t < TK) {
        const int r0 = indices[(b * TK + t) * 2 + 0];
        const int c0 = indices[(b * TK + t) * 2 + 1];
        onode[t] = t + 2 * (c0 - r0) + 1;
    } else if (t < 256) {
        onode[t] = 255;
    }

    {
        const int c4 = t & 31, r8 = t >> 5;
        #pragma unroll
        for (int rr = 0; rr < 4; ++rr) {
            const int row = r8 + rr * 8;
            const int tq = qq * 32 + row;
            float4 f = *(const float4*)(qp + (long)(tq * 4 + b) * 1024 + h * 128 + c4 * 4);
            const unsigned short h0 = f2bf(f.x), h1 = f2bf(f.y), h2 = f2bf(f.z), h3 = f2bf(f.w);
            short4v hv, lv;
            hv[0] = (short)h0; hv[1] = (short)h1; hv[2] = (short)h2; hv[3] = (short)h3;
            lv[0] = (short)f2bf(f.x - bfbits2f(h0));
            lv[1] = (short)f2bf(f.y - bfbits2f(h1));
            lv[2] = (short)f2bf(f.z - bfbits2f(h2));
            lv[3] = (short)f2bf(f.w - bfbits2f(h3));
            const int byte = row * 256 + ((((c4 >> 1) ^ (row & 15)) << 4) | ((c4 & 1) << 3));
            *(short4v*)(lds + F_QH + byte) = hv;
            *(short4v*)(lds + F_QL + byte) = lv;
        }
    }

    f32x4 acc[4][2];
    #pragma unroll
    for (int nb = 0; nb < 4; ++nb)
        #pragma unroll
        for (int j = 0; j < 2; ++j)
            #pragma unroll
            for (int e = 0; e < 4; ++e) acc[nb][j][e] = 0.f;

    #pragma unroll
    for (int nb = 0; nb < 4; ++nb) {
        __syncthreads();
        {
            const int c4 = t & 31, r8 = t >> 5;
            const float* sb = sbuf + (long)b * 256 * 1024 + h * 128 + c4 * 4;
            #pragma unroll
            for (int rr = 0; rr < 8; ++rr) {
                const int nl = r8 + rr * 8;
                const int node = nb * 64 + nl;
                float4 f0 = *(const float4*)(sb + (long)node * 1024);
                float4 f1 = *(const float4*)(sb + (long)onode[node] * 1024);
                float4 f = make_float4(f0.x - f1.x, f0.y - f1.y, f0.z - f1.z, f0.w - f1.w);
                const unsigned short h0 = f2bf(f.x), h1 = f2bf(f.y), h2 = f2bf(f.z), h3 = f2bf(f.w);
                short4v hv, lv;
                hv[0] = (short)h0; hv[1] = (short)h1; hv[2] = (short)h2; hv[3] = (short)h3;
                lv[0] = (short)f2bf(f.x - bfbits2f(h0));
                lv[1] = (short)f2bf(f.y - bfbits2f(h1));
                lv[2] = (short)f2bf(f.z - bfbits2f(h2));
                lv[3] = (short)f2bf(f.w - bfbits2f(h3));
                const int byte = nl * 256 + ((((c4 >> 1) ^ (nl & 15)) << 4) | ((c4 & 1) << 3));
                *(short4v*)(lds + F_KH + byte) = hv;
                *(short4v*)(lds + F_KL + byte) = lv;
            }
        }
        __syncthreads();
        #pragma unroll
        for (int ks = 0; ks < 4; ++ks) {
            short8 ah, al, bh_[2], bl[2];
            {
                const int row = wm * 16 + (lane & 15);
                const int byte = row * 256 + (((ks * 4 + (lane >> 4)) ^ (row & 15)) << 4);
                ah = *(const short8*)(lds + F_QH + byte);
                al = *(const short8*)(lds + F_QL + byte);
            }
            #pragma unroll
            for (int fn = 0; fn < 2; ++fn) {
                const int row = wn * 32 + fn * 16 + (lane & 15);
                const int byte = row * 256 + (((ks * 4 + (lane >> 4)) ^ (row & 15)) << 4);
                bh_[fn] = *(const short8*)(lds + F_KH + byte);
                bl[fn] = *(const short8*)(lds + F_KL + byte);
            }
            #pragma unroll
            for (int fn = 0; fn < 2; ++fn) {
                acc[nb][fn] = __builtin_amdgcn_mfma_f32_16x16x32_bf16(ah, bh_[fn], acc[nb][fn], 0, 0, 0);
                acc[nb][fn] = __builtin_amdgcn_mfma_f32_16x16x32_bf16(al, bh_[fn], acc[nb][fn], 0, 0, 0);
                acc[nb][fn] = __builtin_amdgcn_mfma_f32_16x16x32_bf16(ah, bl[fn], acc[nb][fn], 0, 0, 0);
            }
        }
    }

    float pmax[4] = {-1e30f, -1e30f, -1e30f, -1e30f};
    #pragma unroll
    for (int nb = 0; nb < 4; ++nb)
        #pragma unroll
        for (int fn = 0; fn < 2; ++fn)
            #pragma unroll
            for (int i = 0; i < 4; ++i) {
                const int col = nb * 64 + wn * 32 + fn * 16 + (lane & 15);
                const float s = (col < TK) ? acc[nb][fn][i] : -1e30f;
                pmax[i] = fmaxf(pmax[i], s);
            }
    #pragma unroll
    for (int off = 1; off < 16; off <<= 1)
        #pragma unroll
        for (int i = 0; i < 4; ++i) pmax[i] = fmaxf(pmax[i], __shfl_xor(pmax[i], off));
    if ((lane & 15) == 0) {
        #pragma unroll
        for (int i = 0; i < 4; ++i) {
            const int row = wm * 16 + ((lane >> 4) << 2) + i;
            red[wn * 32 + row] = pmax[i];
        }
    }
    __syncthreads();
    float rm[4];
    #pragma unroll
    for (int i = 0; i < 4; ++i) {
        const int row = wm * 16 + ((lane >> 4) << 2) + i;
        rm[i] = fmaxf(red[row], red[32 + row]);
    }
    float psum[4] = {0.f, 0.f, 0.f, 0.f};
    #pragma unroll
    for (int nb = 0; nb < 4; ++nb)
        #pragma unroll
        for (int fn = 0; fn < 2; ++fn)
            #pragma unroll
            for (int i = 0; i < 4; ++i) {
                const int col = nb * 64 + wn * 32 + fn * 16 + (lane & 15);
                const int row = wm * 16 + ((lane >> 4) << 2) + i;
                float p = 0.f;
                if (col < TK) p = __expf(acc[nb][fn][i] - rm[i]);
                psum[i] += p;
                const unsigned short hp = f2bf(p);
                const unsigned short lp = f2bf(p - bfbits2f(hp));
                const int u = ((col >> 3) ^ ((row & 15) << 1));
                const int byte = row * 512 + (u << 4) + (col & 7) * 2;
                *(unsigned short*)(lds + F_PH + byte) = hp;
                *(unsigned short*)(lds + F_PL + byte) = lp;
            }
    #pragma unroll
    for (int off = 1; off < 16; off <<= 1)
        #pragma unroll
        for (int i = 0; i < 4; ++i) psum[i] += __shfl_xor(psum[i], off);
    if ((lane & 15) == 0) {
        #pragma unroll
        for (int i = 0; i < 4; ++i) {
            const int row = wm * 16 + ((lane >> 4) << 2) + i;
            red[64 + wn * 32 + row] = psum[i];
        }
    }
    __syncthreads();
    if (wn == 0 && (lane & 15) == 0) {
        #pragma unroll
        for (int i = 0; i < 4; ++i) {
            const int row = wm * 16 + ((lane >> 4) << 2) + i;
            inv[row] = 1.f / (red[64 + row] + red[96 + row]);
        }
    }

    f32x4 accO[4];
    #pragma unroll
    for (int fn = 0; fn < 4; ++fn)
        #pragma unroll
        for (int e = 0; e < 4; ++e) accO[fn][e] = 0.f;

    #pragma unroll
    for (int nb = 0; nb < 4; ++nb) {
        __syncthreads();
        {
            const int c4 = t & 31, r8 = t >> 5;
            #pragma unroll
            for (int rr = 0; rr < 8; ++rr) {
                const int nl = r8 + rr * 8;
                const int node = nb * 64 + nl;
                float4 f = make_float4(0.f, 0.f, 0.f, 0.f);
                if (node < TK) f = *(const float4*)(vp + (long)(node * 4 + b) * 1024 + h * 128 + c4 * 4);
                const float fa[4] = {f.x, f.y, f.z, f.w};
                #pragma unroll
                for (int j = 0; j < 4; ++j) {
                    const int d = c4 * 4 + j;
                    const int byte = d * 128 + ((((nl >> 3) ^ (d & 7)) << 4) | ((nl & 7) << 1));
                    *(unsigned short*)(lds + F_KH + byte) = f2bf(fa[j]);
                }
            }
        }
        __syncthreads();
        #pragma unroll
        for (int ks = 0; ks < 2; ++ks) {
            short8 pa, pl, vb[4];
            {
                const int row = wm * 16 + (lane & 15);
                const int u = (nb * 8 + ks * 4 + (lane >> 4)) ^ ((row & 15) << 1);
                const int byte = row * 512 + (u << 4);
                pa = *(const short8*)(lds + F_PH + byte);
                pl = *(const short8*)(lds + F_PL + byte);
            }
            #pragma unroll
            for (int fn = 0; fn < 4; ++fn) {
                const int d = wn * 64 + fn * 16 + (lane & 15);
                const int u = (ks * 4 + (lane >> 4)) ^ (d & 7);
                const int byte = d * 128 + (u << 4);
                vb[fn] = *(const short8*)(lds + F_KH + byte);
            }
            #pragma unroll
            for (int fn = 0; fn < 4; ++fn) {
                accO[fn] = __builtin_amdgcn_mfma_f32_16x16x32_bf16(pa, vb[fn], accO[fn], 0, 0, 0);
                accO[fn] = __builtin_amdgcn_mfma_f32_16x16x32_bf16(pl, vb[fn], accO[fn], 0, 0, 0);
            }
        }
    }

    __syncthreads();
    #pragma unroll
    for (int i = 0; i < 4; ++i) {
        const int row = wm * 16 + ((lane >> 4) << 2) + i;
        const float iv = inv[row];
        const int arow = (qq * 32 + row) * 4 + b;
        #pragma unroll
        for (int fn = 0; fn < 4; ++fn) {
            const int col = h * 128 + wn * 64 + fn * 16 + (lane & 15);
            const float val = accO[fn][i] * iv;
            const unsigned short hv = f2bf(val);
            const unsigned short lv = f2bf(val - bfbits2f(hv));
            apk2[(long)arow * 2048 + col] = hv;
            apk2[(long)arow * 2048 + 1024 + col] = lv;
        }
    }
}

extern "C" void kernel_launch(void* const* d_in, const int* in_sizes, int n_in,
                              void* d_out, int out_size, void* d_ws, size_t ws_size,
                              hipStream_t stream) {
    const float* query   = (const float*)d_in[0];
    const float* key_t   = (const float*)d_in[1];
    const float* value   = (const float*)d_in[2];
    const int*   indices = (const int*)d_in[3];
    const float* ipw     = (const float*)d_in[4];
    const float* ipb     = (const float*)d_in[5];
    const float* opw     = (const float*)d_in[6];
    const float* opb     = (const float*)d_in[7];
    float* out = (float*)d_out;

    float* ws = (float*)d_ws;
    float* kp   = ws;                        // [1024][1024]
    float* vp   = kp + 1048576;              // [1024][1024]
    float* qp   = vp + 1048576;              // [512][1024]
    float* sbuf = qp + 524288;               // [4][256][1024] suffix sums
    unsigned short* apk  = (unsigned short*)(sbuf + 1048576);  // [2560][2048]
    unsigned short* wpk  = apk + 2560L * 2048;                 // [4096][2048]
    unsigned short* apk2 = apk;              // overlay (apk dead after qkvb)

    const float qscale = 0.08838834764831843f;  // 128^-0.5

    pack_all<<<dim3(2048), 256, 0, stream>>>(query, key_t, value, ipw, opw, apk, wpk);

    qkvb_kernel<<<dim3(16, 40), 256, 0, stream>>>(apk, wpk, ipb, qp, kp, vp, qscale);

    ksuffix_kernel<<<dim3(32, 4), 256, 0, stream>>>(kp, sbuf);

    fused_attn_kernel<<<dim3(128), 256, 0, stream>>>(qp, sbuf, vp, indices, apk2);

    outprojb_kernel<<<dim3(16, 8), 256, 0, stream>>>(apk2, wpk, opb, out);
}

// Round 9
// 92.952 us; speedup vs baseline: 1.2931x; 1.0177x over previous
//
#include <hip/hip_runtime.h>
#include <math.h>

#define EMBED 1024
#define NHEAD 8
#define HDIM 128
#define TK 255
#define BATCH 4
#define LQ 128
#define BH 32

typedef __attribute__((ext_vector_type(4))) float f32x4;
typedef __attribute__((ext_vector_type(8))) short short8;
typedef __attribute__((ext_vector_type(4))) short short4v;

static __device__ __forceinline__ unsigned short f2bf(float f) {
    unsigned u = __float_as_uint(f);
    u += 0x7FFFu + ((u >> 16) & 1u);
    return (unsigned short)(u >> 16);
}
static __device__ __forceinline__ float bfbits2f(unsigned short s) {
    return __uint_as_float(((unsigned)s) << 16);
}

// ============ pack: fp32 [rows][1024] -> bf16 [rows][2048] = [hi | lo] ============
__global__ __launch_bounds__(256) void pack_all(
    const float* __restrict__ query, const float* __restrict__ key_t,
    const float* __restrict__ value, const float* __restrict__ ipw,
    const float* __restrict__ opw,
    unsigned short* __restrict__ apk, unsigned short* __restrict__ wpk)
{
    const int APKC = 2560 * 256;
    const int TOT = APKC + 4096 * 256;
    for (int idx = blockIdx.x * 256 + threadIdx.x; idx < TOT; idx += gridDim.x * 256) {
        const bool isA = idx < APKC;
        const int rel = isA ? idx : idx - APKC;
        const int row = rel >> 8, c4 = rel & 255;
        const float* src = nullptr; long srow = 0;
        unsigned short* dst;
        if (isA) {
            dst = apk + (long)row * 2048;
            if (row < 512) { src = query; srow = row; }
            else if (row < 1536) { if (row - 512 < 1020) { src = key_t; srow = row - 512; } }
            else { if (row - 1536 < 1020) { src = value; srow = row - 1536; } }
        } else {
            dst = wpk + (long)row * 2048;
            if (row < 3072) { src = ipw; srow = row; }
            else { src = opw; srow = row - 3072; }
        }
        float4 f = make_float4(0.f, 0.f, 0.f, 0.f);
        if (src) f = *(const float4*)(src + srow * 1024 + c4 * 4);
        const unsigned short h0 = f2bf(f.x), h1 = f2bf(f.y), h2 = f2bf(f.z), h3 = f2bf(f.w);
        short4v hv, lv;
        hv[0] = (short)h0; hv[1] = (short)h1; hv[2] = (short)h2; hv[3] = (short)h3;
        lv[0] = (short)f2bf(f.x - bfbits2f(h0));
        lv[1] = (short)f2bf(f.y - bfbits2f(h1));
        lv[2] = (short)f2bf(f.z - bfbits2f(h2));
        lv[3] = (short)f2bf(f.w - bfbits2f(h3));
        *(short4v*)(dst + c4 * 4) = hv;
        *(short4v*)(dst + 1024 + c4 * 4) = lv;
    }
}

// ============ bgemm2: all-plane BK=64 staging, TERMS MFMAs per fragment pair ============
template<int BM, int BN, int TERMS>
__device__ __forceinline__ void bgemm2(
    const unsigned short* __restrict__ A,
    const unsigned short* __restrict__ B,
    const float* __restrict__ bias,
    float* __restrict__ C, long ldc, float scale,
    int m0, int n0, unsigned char* lds)
{
    constexpr int AH = 0;
    constexpr int AL = BM * 128;
    constexpr int BHo = 2 * BM * 128;
    constexpr int BLo = BHo + BN * 128;
    constexpr int FM2 = BM / 32, FN2 = BN / 32;
    constexpr int CA = BM / 32;
    constexpr int CB = BN / 32;
    const int t = threadIdx.x, lane = t & 63, wave = t >> 6;
    const int wm = wave >> 1, wn = wave & 1;

    f32x4 acc[FM2][FN2];
    #pragma unroll
    for (int i = 0; i < FM2; ++i)
        #pragma unroll
        for (int j = 0; j < FN2; ++j)
            #pragma unroll
            for (int e = 0; e < 4; ++e) acc[i][j][e] = 0.f;

    const int srow_a = t >> 3, su = t & 7;
    short8 rah[CA], ral[CA], rbh[CB], rbl[CB];

    #pragma unroll
    for (int c = 0; c < CA; ++c) {
        const long base = (long)(m0 + c * 32 + srow_a) * 2048 + su * 8;
        rah[c] = *(const short8*)(A + base);
        ral[c] = *(const short8*)(A + base + 1024);
    }
    #pragma unroll
    for (int c = 0; c < CB; ++c) {
        const long base = (long)(n0 + c * 32 + srow_a) * 2048 + su * 8;
        rbh[c] = *(const short8*)(B + base);
        if (TERMS == 3) rbl[c] = *(const short8*)(B + base + 1024);
    }

    for (int kt = 0; kt < 16; ++kt) {
        #pragma unroll
        for (int c = 0; c < CA; ++c) {
            const int row = c * 32 + srow_a;
            const int byte = row * 128 + ((su ^ (row & 7)) << 4);
            *(short8*)(lds + AH + byte) = rah[c];
            *(short8*)(lds + AL + byte) = ral[c];
        }
        #pragma unroll
        for (int c = 0; c < CB; ++c) {
            const int row = c * 32 + srow_a;
            const int byte = row * 128 + ((su ^ (row & 7)) << 4);
            *(short8*)(lds + BHo + byte) = rbh[c];
            if (TERMS == 3) *(short8*)(lds + BLo + byte) = rbl[c];
        }
        __syncthreads();
        if (kt + 1 < 16) {
            const int off = (kt + 1) * 64;
            #pragma unroll
            for (int c = 0; c < CA; ++c) {
                const long base = (long)(m0 + c * 32 + srow_a) * 2048 + off + su * 8;
                rah[c] = *(const short8*)(A + base);
                ral[c] = *(const short8*)(A + base + 1024);
            }
            #pragma unroll
            for (int c = 0; c < CB; ++c) {
                const long base = (long)(n0 + c * 32 + srow_a) * 2048 + off + su * 8;
                rbh[c] = *(const short8*)(B + base);
                if (TERMS == 3) rbl[c] = *(const short8*)(B + base + 1024);
            }
        }
        #pragma unroll
        for (int ks = 0; ks < 2; ++ks) {
            short8 afh[FM2], afl[FM2], bgh[FN2], bgl[FN2];
            #pragma unroll
            for (int fm = 0; fm < FM2; ++fm) {
                const int row = wm * (BM / 2) + fm * 16 + (lane & 15);
                const int byte = row * 128 + (((ks * 4 + (lane >> 4)) ^ (row & 7)) << 4);
                afh[fm] = *(const short8*)(lds + AH + byte);
                afl[fm] = *(const short8*)(lds + AL + byte);
            }
            #pragma unroll
            for (int fn = 0; fn < FN2; ++fn) {
                const int row = wn * (BN / 2) + fn * 16 + (lane & 15);
                const int byte = row * 128 + (((ks * 4 + (lane >> 4)) ^ (row & 7)) << 4);
                bgh[fn] = *(const short8*)(lds + BHo + byte);
                if (TERMS == 3) bgl[fn] = *(const short8*)(lds + BLo + byte);
            }
            #pragma unroll
            for (int fm = 0; fm < FM2; ++fm)
                #pragma unroll
                for (int fn = 0; fn < FN2; ++fn) {
                    acc[fm][fn] = __builtin_amdgcn_mfma_f32_16x16x32_bf16(afh[fm], bgh[fn], acc[fm][fn], 0, 0, 0);
                    acc[fm][fn] = __builtin_amdgcn_mfma_f32_16x16x32_bf16(afl[fm], bgh[fn], acc[fm][fn], 0, 0, 0);
                    if (TERMS == 3)
                        acc[fm][fn] = __builtin_amdgcn_mfma_f32_16x16x32_bf16(afh[fm], bgl[fn], acc[fm][fn], 0, 0, 0);
                }
        }
        __syncthreads();
    }

    #pragma unroll
    for (int fm = 0; fm < FM2; ++fm)
        #pragma unroll
        for (int i = 0; i < 4; ++i) {
            const int m = m0 + wm * (BM / 2) + fm * 16 + ((lane >> 4) << 2) + i;
            #pragma unroll
            for (int fn = 0; fn < FN2; ++fn) {
                const int n = n0 + wn * (BN / 2) + fn * 16 + (lane & 15);
                float v = acc[fm][fn][i];
                if (bias) v += bias[n];
                C[(long)m * ldc + n] = v * scale;
            }
        }
}

// ---- fused q/k/v projections, 64x64 tiles, XCD-swizzled. grid (16, 40) = 640 = 8*80
__global__ __launch_bounds__(256) void qkvb_kernel(
    const unsigned short* __restrict__ apk, const unsigned short* __restrict__ wpk,
    const float* __restrict__ ipb,
    float* __restrict__ qp, float* __restrict__ kp, float* __restrict__ vp, float qscale)
{
    __shared__ __align__(16) unsigned char lds[4 * 64 * 128];
    // XCD swizzle: dispatch id lid -> cluster 5 consecutive y-rows per XCD
    const int lid = blockIdx.y * 16 + blockIdx.x;
    const int xcd = lid & 7, slot = lid >> 3;        // slot in [0,80)
    const int y = xcd * 5 + (slot >> 4);
    const int x = slot & 15;
    if (y < 8) {
        bgemm2<64, 64, 3>(apk, wpk, ipb, qp, 1024, qscale,
                          y * 64, x * 64, lds);
    } else if (y < 24) {
        bgemm2<64, 64, 3>(apk + 512L * 2048, wpk + 1024L * 2048, ipb + 1024, kp, 1024, 1.f,
                          (y - 8) * 64, x * 64, lds);
    } else {
        bgemm2<64, 64, 2>(apk + 1536L * 2048, wpk + 2048L * 2048, ipb + 2048, vp, 1024, 1.f,
                          (y - 24) * 64, x * 64, lds);
    }
}

// ---- out projection, 64x64 tiles, 2-term, XCD-swizzled. grid (16, 8) = 128
__global__ __launch_bounds__(256) void outprojb_kernel(
    const unsigned short* __restrict__ apk2, const unsigned short* __restrict__ wpk,
    const float* __restrict__ opb, float* __restrict__ out)
{
    __shared__ __align__(16) unsigned char lds[3 * 64 * 128];
    const int lid = blockIdx.y * 16 + blockIdx.x;
    const int y = lid & 7, x = lid >> 3;             // same-y clustered per XCD
    bgemm2<64, 64, 2>(apk2, wpk + 3072L * 2048, opb, out, 1024, 1.f,
                      y * 64, x * 64, lds);
}

// ============ ksuffix: sbuf[b][n][e] = sum_{m=n..254} kp[(m*4+b)][e], sbuf[b][255][e]=0 ====
__global__ __launch_bounds__(256) void ksuffix_kernel(
    const float* __restrict__ kp, float* __restrict__ sbuf)
{
    const int b = blockIdx.y;
    const int cl = threadIdx.x & 31;
    const int e = blockIdx.x * 32 + cl;
    const int seg = threadIdx.x >> 5;
    __shared__ float tot[8][33];
    float acc = 0.f;
    const int nhi = seg * 32 + 31;
    #pragma unroll 8
    for (int i = 0; i < 32; ++i) {
        const int n = nhi - i;
        float v = 0.f;
        if (n < TK) v = kp[(long)(n * 4 + b) * 1024 + e];
        acc += v;
        sbuf[((long)b * 256 + n) * 1024 + e] = acc;
    }
    tot[seg][cl] = acc;
    __syncthreads();
    float add = 0.f;
    #pragma unroll
    for (int s = 0; s < 8; ++s) if (s > seg) add += tot[s][cl];
    if (seg < 7) {
        #pragma unroll 8
        for (int i = 0; i < 32; ++i) {
            const int n = seg * 32 + i;
            sbuf[((long)b * 256 + n) * 1024 + e] += add;
        }
    }
}

// ============ fused attention, 4-way q split, 2 blocks/CU. grid 128, XCD-swizzled ====
// LDS: QH 8K | QL 8K | KH 16K (Vt overlay) | KL 16K | PH 16K | RED 512B | INV 128B
#define F_QH 0
#define F_QL 8192
#define F_KH 16384
#define F_KL 32768
#define F_PH 49152
#define F_RED 65536
#define F_INV 66048

__global__ __launch_bounds__(256, 2) void fused_attn_kernel(
    const float* __restrict__ qp, const float* __restrict__ sbuf,
    const float* __restrict__ vp, const int* __restrict__ indices,
    unsigned short* __restrict__ apk2)
{
    __shared__ __align__(16) unsigned char lds[66176];
    __shared__ int onode[256];
    // XCD swizzle: cluster the 4 qq-siblings (sharing K/V/sbuf) on one XCD
    const int lid = blockIdx.x;
    const int xcd = lid & 7, slot = lid >> 3;        // slot in [0,16)
    const int bh = xcd * 4 + (slot >> 2), qq = slot & 3;
    const int b = bh >> 3, h = bh & 7;
    const int t = threadIdx.x, lane = t & 63, wave = t >> 6;
    const int wm = wave >> 1, wn = wave & 1;
    float* red = (float*)(lds + F_RED);
    float* inv = (float*)(lds + F_INV);

    if (t < TK) {
        const int r0 = indices[(b * TK + t) * 2 + 0];
        const int c0 = indices[(b * TK + t) * 2 + 1];
        onode[t] = t + 2 * (c0 - r0) + 1;
    } else if (t < 256) {
        onode[t] = 255;
    }

    {
        const int c4 = t & 31, r8 = t >> 5;
        #pragma unroll
        for (int rr = 0; rr < 4; ++rr) {
            const int row = r8 + rr * 8;
            const int tq = qq * 32 + row;
            float4 f = *(const float4*)(qp + (long)(tq * 4 + b) * 1024 + h * 128 + c4 * 4);
            const unsigned short h0 = f2bf(f.x), h1 = f2bf(f.y), h2 = f2bf(f.z), h3 = f2bf(f.w);
            short4v hv, lv;
            hv[0] = (short)h0; hv[1] = (short)h1; hv[2] = (short)h2; hv[3] = (short)h3;
            lv[0] = (short)f2bf(f.x - bfbits2f(h0));
            lv[1] = (short)f2bf(f.y - bfbits2f(h1));
            lv[2] = (short)f2bf(f.z - bfbits2f(h2));
            lv[3] = (short)f2bf(f.w - bfbits2f(h3));
            const int byte = row * 256 + ((((c4 >> 1) ^ (row & 15)) << 4) | ((c4 & 1) << 3));
            *(short4v*)(lds + F_QH + byte) = hv;
            *(short4v*)(lds + F_QL + byte) = lv;
        }
    }

    f32x4 acc[4][2];
    #pragma unroll
    for (int nb = 0; nb < 4; ++nb)
        #pragma unroll
        for (int j = 0; j < 2; ++j)
            #pragma unroll
            for (int e = 0; e < 4; ++e) acc[nb][j][e] = 0.f;

    #pragma unroll
    for (int nb = 0; nb < 4; ++nb) {
        __syncthreads();
        {
            const int c4 = t & 31, r8 = t >> 5;
            const float* sb = sbuf + (long)b * 256 * 1024 + h * 128 + c4 * 4;
            #pragma unroll
            for (int rr = 0; rr < 8; ++rr) {
                const int nl = r8 + rr * 8;
                const int node = nb * 64 + nl;
                float4 f0 = *(const float4*)(sb + (long)node * 1024);
                float4 f1 = *(const float4*)(sb + (long)onode[node] * 1024);
                float4 f = make_float4(f0.x - f1.x, f0.y - f1.y, f0.z - f1.z, f0.w - f1.w);
                const unsigned short h0 = f2bf(f.x), h1 = f2bf(f.y), h2 = f2bf(f.z), h3 = f2bf(f.w);
                short4v hv, lv;
                hv[0] = (short)h0; hv[1] = (short)h1; hv[2] = (short)h2; hv[3] = (short)h3;
                lv[0] = (short)f2bf(f.x - bfbits2f(h0));
                lv[1] = (short)f2bf(f.y - bfbits2f(h1));
                lv[2] = (short)f2bf(f.z - bfbits2f(h2));
                lv[3] = (short)f2bf(f.w - bfbits2f(h3));
                const int byte = nl * 256 + ((((c4 >> 1) ^ (nl & 15)) << 4) | ((c4 & 1) << 3));
                *(short4v*)(lds + F_KH + byte) = hv;
                *(short4v*)(lds + F_KL + byte) = lv;
            }
        }
        __syncthreads();
        #pragma unroll
        for (int ks = 0; ks < 4; ++ks) {
            short8 ah, al, bh_[2], bl[2];
            {
                const int row = wm * 16 + (lane & 15);
                const int byte = row * 256 + (((ks * 4 + (lane >> 4)) ^ (row & 15)) << 4);
                ah = *(const short8*)(lds + F_QH + byte);
                al = *(const short8*)(lds + F_QL + byte);
            }
            #pragma unroll
            for (int fn = 0; fn < 2; ++fn) {
                const int row = wn * 32 + fn * 16 + (lane & 15);
                const int byte = row * 256 + (((ks * 4 + (lane >> 4)) ^ (row & 15)) << 4);
                bh_[fn] = *(const short8*)(lds + F_KH + byte);
                bl[fn] = *(const short8*)(lds + F_KL + byte);
            }
            #pragma unroll
            for (int fn = 0; fn < 2; ++fn) {
                acc[nb][fn] = __builtin_amdgcn_mfma_f32_16x16x32_bf16(ah, bh_[fn], acc[nb][fn], 0, 0, 0);
                acc[nb][fn] = __builtin_amdgcn_mfma_f32_16x16x32_bf16(al, bh_[fn], acc[nb][fn], 0, 0, 0);
                acc[nb][fn] = __builtin_amdgcn_mfma_f32_16x16x32_bf16(ah, bl[fn], acc[nb][fn], 0, 0, 0);
            }
        }
    }

    float pmax[4] = {-1e30f, -1e30f, -1e30f, -1e30f};
    #pragma unroll
    for (int nb = 0; nb < 4; ++nb)
        #pragma unroll
        for (int fn = 0; fn < 2; ++fn)
            #pragma unroll
            for (int i = 0; i < 4; ++i) {
                const int col = nb * 64 + wn * 32 + fn * 16 + (lane & 15);
                const float s = (col < TK) ? acc[nb][fn][i] : -1e30f;
                pmax[i] = fmaxf(pmax[i], s);
            }
    #pragma unroll
    for (int off = 1; off < 16; off <<= 1)
        #pragma unroll
        for (int i = 0; i < 4; ++i) pmax[i] = fmaxf(pmax[i], __shfl_xor(pmax[i], off));
    if ((lane & 15) == 0) {
        #pragma unroll
        for (int i = 0; i < 4; ++i) {
            const int row = wm * 16 + ((lane >> 4) << 2) + i;
            red[wn * 32 + row] = pmax[i];
        }
    }
    __syncthreads();
    float rm[4];
    #pragma unroll
    for (int i = 0; i < 4; ++i) {
        const int row = wm * 16 + ((lane >> 4) << 2) + i;
        rm[i] = fmaxf(red[row], red[32 + row]);
    }
    float psum[4] = {0.f, 0.f, 0.f, 0.f};
    #pragma unroll
    for (int nb = 0; nb < 4; ++nb)
        #pragma unroll
        for (int fn = 0; fn < 2; ++fn)
            #pragma unroll
            for (int i = 0; i < 4; ++i) {
                const int col = nb * 64 + wn * 32 + fn * 16 + (lane & 15);
                const int row = wm * 16 + ((lane >> 4) << 2) + i;
                float p = 0.f;
                if (col < TK) p = __expf(acc[nb][fn][i] - rm[i]);
                psum[i] += p;
                const unsigned short hp = f2bf(p);
                const int u = ((col >> 3) ^ ((row & 15) << 1));
                const int byte = row * 512 + (u << 4) + (col & 7) * 2;
                *(unsigned short*)(lds + F_PH + byte) = hp;
            }
    #pragma unroll
    for (int off = 1; off < 16; off <<= 1)
        #pragma unroll
        for (int i = 0; i < 4; ++i) psum[i] += __shfl_xor(psum[i], off);
    if ((lane & 15) == 0) {
        #pragma unroll
        for (int i = 0; i < 4; ++i) {
            const int row = wm * 16 + ((lane >> 4) << 2) + i;
            red[64 + wn * 32 + row] = psum[i];
        }
    }
    __syncthreads();
    if (wn == 0 && (lane & 15) == 0) {
        #pragma unroll
        for (int i = 0; i < 4; ++i) {
            const int row = wm * 16 + ((lane >> 4) << 2) + i;
            inv[row] = 1.f / (red[64 + row] + red[96 + row]);
        }
    }

    f32x4 accO[4];
    #pragma unroll
    for (int fn = 0; fn < 4; ++fn)
        #pragma unroll
        for (int e = 0; e < 4; ++e) accO[fn][e] = 0.f;

    #pragma unroll
    for (int nb = 0; nb < 4; ++nb) {
        __syncthreads();
        {
            const int c4 = t & 31, r8 = t >> 5;
            #pragma unroll
            for (int rr = 0; rr < 8; ++rr) {
                const int nl = r8 + rr * 8;
                const int node = nb * 64 + nl;
                float4 f = make_float4(0.f, 0.f, 0.f, 0.f);
                if (node < TK) f = *(const float4*)(vp + (long)(node * 4 + b) * 1024 + h * 128 + c4 * 4);
                const float fa[4] = {f.x, f.y, f.z, f.w};
                #pragma unroll
                for (int j = 0; j < 4; ++j) {
                    const int d = c4 * 4 + j;
                    const int byte = d * 128 + ((((nl >> 3) ^ (d & 7)) << 4) | ((nl & 7) << 1));
                    *(unsigned short*)(lds + F_KH + byte) = f2bf(fa[j]);
                }
            }
        }
        __syncthreads();
        #pragma unroll
        for (int ks = 0; ks < 2; ++ks) {
            short8 pa, vb[4];
            {
                const int row = wm * 16 + (lane & 15);
                const int u = (nb * 8 + ks * 4 + (lane >> 4)) ^ ((row & 15) << 1);
                const int byte = row * 512 + (u << 4);
                pa = *(const short8*)(lds + F_PH + byte);
            }
            #pragma unroll
            for (int fn = 0; fn < 4; ++fn) {
                const int d = wn * 64 + fn * 16 + (lane & 15);
                const int u = (ks * 4 + (lane >> 4)) ^ (d & 7);
                const int byte = d * 128 + (u << 4);
                vb[fn] = *(const short8*)(lds + F_KH + byte);
            }
            #pragma unroll
            for (int fn = 0; fn < 4; ++fn)
                accO[fn] = __builtin_amdgcn_mfma_f32_16x16x32_bf16(pa, vb[fn], accO[fn], 0, 0, 0);
        }
    }

    __syncthreads();
    #pragma unroll
    for (int i = 0; i < 4; ++i) {
        const int row = wm * 16 + ((lane >> 4) << 2) + i;
        const float iv = inv[row];
        const int arow = (qq * 32 + row) * 4 + b;
        #pragma unroll
        for (int fn = 0; fn < 4; ++fn) {
            const int col = h * 128 + wn * 64 + fn * 16 + (lane & 15);
            const float val = accO[fn][i] * iv;
            const unsigned short hv = f2bf(val);
            const unsigned short lv = f2bf(val - bfbits2f(hv));
            apk2[(long)arow * 2048 + col] = hv;
            apk2[(long)arow * 2048 + 1024 + col] = lv;
        }
    }
}

extern "C" void kernel_launch(void* const* d_in, const int* in_sizes, int n_in,
                              void* d_out, int out_size, void* d_ws, size_t ws_size,
                              hipStream_t stream) {
    const float* query   = (const float*)d_in[0];
    const float* key_t   = (const float*)d_in[1];
    const float* value   = (const float*)d_in[2];
    const int*   indices = (const int*)d_in[3];
    const float* ipw     = (const float*)d_in[4];
    const float* ipb     = (const float*)d_in[5];
    const float* opw     = (const float*)d_in[6];
    const float* opb     = (const float*)d_in[7];
    float* out = (float*)d_out;

    float* ws = (float*)d_ws;
    float* kp   = ws;                        // [1024][1024]
    float* vp   = kp + 1048576;              // [1024][1024]
    float* qp   = vp + 1048576;              // [512][1024]
    float* sbuf = qp + 524288;               // [4][256][1024] suffix sums
    unsigned short* apk  = (unsigned short*)(sbuf + 1048576);  // [2560][2048]
    unsigned short* wpk  = apk + 2560L * 2048;                 // [4096][2048]
    unsigned short* apk2 = apk;              // overlay (apk dead after qkvb)

    const float qscale = 0.08838834764831843f;  // 128^-0.5

    pack_all<<<dim3(2048), 256, 0, stream>>>(query, key_t, value, ipw, opw, apk, wpk);

    qkvb_kernel<<<dim3(16, 40), 256, 0, stream>>>(apk, wpk, ipb, qp, kp, vp, qscale);

    ksuffix_kernel<<<dim3(32, 4), 256, 0, stream>>>(kp, sbuf);

    fused_attn_kernel<<<dim3(128), 256, 0, stream>>>(qp, sbuf, vp, indices, apk2);

    outprojb_kernel<<<dim3(16, 8), 256, 0, stream>>>(apk2, wpk, opb, out);
}

// Round 10
// 88.366 us; speedup vs baseline: 1.3602x; 1.0519x over previous
//
#include <hip/hip_runtime.h>
#include <math.h>

#define EMBED 1024
#define NHEAD 8
#define HDIM 128
#define TK 255
#define BATCH 4
#define LQ 128
#define BH 32

typedef __attribute__((ext_vector_type(4))) float f32x4;
typedef __attribute__((ext_vector_type(8))) short short8;
typedef __attribute__((ext_vector_type(4))) short short4v;

static __device__ __forceinline__ unsigned short f2bf(float f) {
    unsigned u = __float_as_uint(f);
    u += 0x7FFFu + ((u >> 16) & 1u);
    return (unsigned short)(u >> 16);
}
static __device__ __forceinline__ float bfbits2f(unsigned short s) {
    return __uint_as_float(((unsigned)s) << 16);
}

// ============ rawsuffix: ssp[b][n][e] = sum_{m=n..254} key_t[m][b][e]; ssp[b][255]=0 ====
__global__ __launch_bounds__(256) void rawsuffix_kernel(
    const float* __restrict__ key_t, float* __restrict__ ssp)
{
    const int b = blockIdx.y;
    const int cl = threadIdx.x & 31;
    const int e = blockIdx.x * 32 + cl;
    const int seg = threadIdx.x >> 5;       // 0..7
    __shared__ float tot[8][33];
    float acc = 0.f;
    const int nhi = seg * 32 + 31;
    #pragma unroll 8
    for (int i = 0; i < 32; ++i) {
        const int n = nhi - i;
        float v = 0.f;
        if (n < TK) v = key_t[(long)(n * 4 + b) * 1024 + e];
        acc += v;
        ssp[((long)b * 256 + n) * 1024 + e] = acc;
    }
    tot[seg][cl] = acc;
    __syncthreads();
    float add = 0.f;
    #pragma unroll
    for (int s = 0; s < 8; ++s) if (s > seg) add += tot[s][cl];
    if (seg < 7) {
        #pragma unroll 8
        for (int i = 0; i < 32; ++i) {
            const int n = seg * 32 + i;
            ssp[((long)b * 256 + n) * 1024 + e] += add;
        }
    }
}

// ============ pack: fp32 -> bf16 [hi | lo]. A: query(512) | ssp(1024) | value(1020+pad).
// W: ipw(3072) | opw(1024); lo-plane skipped for rows >= 2048 (2-term GEMMs never read it).
__global__ __launch_bounds__(256) void pack_all(
    const float* __restrict__ query, const float* __restrict__ ssp,
    const float* __restrict__ value, const float* __restrict__ ipw,
    const float* __restrict__ opw,
    unsigned short* __restrict__ apk, unsigned short* __restrict__ wpk)
{
    const int APKC = 2560 * 256;
    const int TOT = APKC + 4096 * 256;
    for (int idx = blockIdx.x * 256 + threadIdx.x; idx < TOT; idx += gridDim.x * 256) {
        const bool isA = idx < APKC;
        const int rel = isA ? idx : idx - APKC;
        const int row = rel >> 8, c4 = rel & 255;
        const float* src = nullptr; long srow = 0;
        unsigned short* dst;
        bool wlo = true;
        if (isA) {
            dst = apk + (long)row * 2048;
            if (row < 512) { src = query; srow = row; }
            else if (row < 1536) { src = ssp; srow = row - 512; }
            else { if (row - 1536 < 1020) { src = value; srow = row - 1536; } }
        } else {
            dst = wpk + (long)row * 2048;
            if (row < 3072) { src = ipw; srow = row; }
            else { src = opw; srow = row - 3072; }
            wlo = (row < 2048);
        }
        float4 f = make_float4(0.f, 0.f, 0.f, 0.f);
        if (src) f = *(const float4*)(src + srow * 1024 + c4 * 4);
        const unsigned short h0 = f2bf(f.x), h1 = f2bf(f.y), h2 = f2bf(f.z), h3 = f2bf(f.w);
        short4v hv;
        hv[0] = (short)h0; hv[1] = (short)h1; hv[2] = (short)h2; hv[3] = (short)h3;
        *(short4v*)(dst + c4 * 4) = hv;
        if (wlo) {
            short4v lv;
            lv[0] = (short)f2bf(f.x - bfbits2f(h0));
            lv[1] = (short)f2bf(f.y - bfbits2f(h1));
            lv[2] = (short)f2bf(f.z - bfbits2f(h2));
            lv[3] = (short)f2bf(f.w - bfbits2f(h3));
            *(short4v*)(dst + 1024 + c4 * 4) = lv;
        }
    }
}

// ============ bgemm2: all-plane BK=64 staging, TERMS MFMAs per fragment pair ============
// EPI 0: C = (acc + bias[n]) * scale.  EPI 1: C = acc + (255 - (m&255)) * bias[n].
template<int BM, int BN, int TERMS, int EPI>
__device__ __forceinline__ void bgemm2(
    const unsigned short* __restrict__ A,
    const unsigned short* __restrict__ B,
    const float* __restrict__ bias,
    float* __restrict__ C, long ldc, float scale,
    int m0, int n0, unsigned char* lds)
{
    constexpr int AH = 0;
    constexpr int AL = BM * 128;
    constexpr int BHo = 2 * BM * 128;
    constexpr int BLo = BHo + BN * 128;
    constexpr int FM2 = BM / 32, FN2 = BN / 32;
    constexpr int CA = BM / 32;
    constexpr int CB = BN / 32;
    const int t = threadIdx.x, lane = t & 63, wave = t >> 6;
    const int wm = wave >> 1, wn = wave & 1;

    f32x4 acc[FM2][FN2];
    #pragma unroll
    for (int i = 0; i < FM2; ++i)
        #pragma unroll
        for (int j = 0; j < FN2; ++j)
            #pragma unroll
            for (int e = 0; e < 4; ++e) acc[i][j][e] = 0.f;

    const int srow_a = t >> 3, su = t & 7;
    short8 rah[CA], ral[CA], rbh[CB], rbl[CB];

    #pragma unroll
    for (int c = 0; c < CA; ++c) {
        const long base = (long)(m0 + c * 32 + srow_a) * 2048 + su * 8;
        rah[c] = *(const short8*)(A + base);
        ral[c] = *(const short8*)(A + base + 1024);
    }
    #pragma unroll
    for (int c = 0; c < CB; ++c) {
        const long base = (long)(n0 + c * 32 + srow_a) * 2048 + su * 8;
        rbh[c] = *(const short8*)(B + base);
        if (TERMS == 3) rbl[c] = *(const short8*)(B + base + 1024);
    }

    for (int kt = 0; kt < 16; ++kt) {
        #pragma unroll
        for (int c = 0; c < CA; ++c) {
            const int row = c * 32 + srow_a;
            const int byte = row * 128 + ((su ^ (row & 7)) << 4);
            *(short8*)(lds + AH + byte) = rah[c];
            *(short8*)(lds + AL + byte) = ral[c];
        }
        #pragma unroll
        for (int c = 0; c < CB; ++c) {
            const int row = c * 32 + srow_a;
            const int byte = row * 128 + ((su ^ (row & 7)) << 4);
            *(short8*)(lds + BHo + byte) = rbh[c];
            if (TERMS == 3) *(short8*)(lds + BLo + byte) = rbl[c];
        }
        __syncthreads();
        if (kt + 1 < 16) {
            const int off = (kt + 1) * 64;
            #pragma unroll
            for (int c = 0; c < CA; ++c) {
                const long base = (long)(m0 + c * 32 + srow_a) * 2048 + off + su * 8;
                rah[c] = *(const short8*)(A + base);
                ral[c] = *(const short8*)(A + base + 1024);
            }
            #pragma unroll
            for (int c = 0; c < CB; ++c) {
                const long base = (long)(n0 + c * 32 + srow_a) * 2048 + off + su * 8;
                rbh[c] = *(const short8*)(B + base);
                if (TERMS == 3) rbl[c] = *(const short8*)(B + base + 1024);
            }
        }
        #pragma unroll
        for (int ks = 0; ks < 2; ++ks) {
            short8 afh[FM2], afl[FM2], bgh[FN2], bgl[FN2];
            #pragma unroll
            for (int fm = 0; fm < FM2; ++fm) {
                const int row = wm * (BM / 2) + fm * 16 + (lane & 15);
                const int byte = row * 128 + (((ks * 4 + (lane >> 4)) ^ (row & 7)) << 4);
                afh[fm] = *(const short8*)(lds + AH + byte);
                afl[fm] = *(const short8*)(lds + AL + byte);
            }
            #pragma unroll
            for (int fn = 0; fn < FN2; ++fn) {
                const int row = wn * (BN / 2) + fn * 16 + (lane & 15);
                const int byte = row * 128 + (((ks * 4 + (lane >> 4)) ^ (row & 7)) << 4);
                bgh[fn] = *(const short8*)(lds + BHo + byte);
                if (TERMS == 3) bgl[fn] = *(const short8*)(lds + BLo + byte);
            }
            #pragma unroll
            for (int fm = 0; fm < FM2; ++fm)
                #pragma unroll
                for (int fn = 0; fn < FN2; ++fn) {
                    acc[fm][fn] = __builtin_amdgcn_mfma_f32_16x16x32_bf16(afh[fm], bgh[fn], acc[fm][fn], 0, 0, 0);
                    acc[fm][fn] = __builtin_amdgcn_mfma_f32_16x16x32_bf16(afl[fm], bgh[fn], acc[fm][fn], 0, 0, 0);
                    if (TERMS == 3)
                        acc[fm][fn] = __builtin_amdgcn_mfma_f32_16x16x32_bf16(afh[fm], bgl[fn], acc[fm][fn], 0, 0, 0);
                }
        }
        __syncthreads();
    }

    #pragma unroll
    for (int fm = 0; fm < FM2; ++fm)
        #pragma unroll
        for (int i = 0; i < 4; ++i) {
            const int m = m0 + wm * (BM / 2) + fm * 16 + ((lane >> 4) << 2) + i;
            #pragma unroll
            for (int fn = 0; fn < FN2; ++fn) {
                const int n = n0 + wn * (BN / 2) + fn * 16 + (lane & 15);
                float v = acc[fm][fn][i];
                if (EPI == 0) {
                    if (bias) v += bias[n];
                    v *= scale;
                } else {
                    v += (float)(255 - (m & 255)) * bias[n];
                }
                C[(long)m * ldc + n] = v;
            }
        }
}

// ---- fused q/k(suffix)/v projections, 64x64 tiles, XCD-swizzled. grid (16, 40)
// y<8: Q (512 rows). y<24: suffix-K -> sbuf directly (1024 rows, rowcount bias). else V.
__global__ __launch_bounds__(256) void qkvb_kernel(
    const unsigned short* __restrict__ apk, const unsigned short* __restrict__ wpk,
    const float* __restrict__ ipb,
    float* __restrict__ qp, float* __restrict__ sbuf, float* __restrict__ vp, float qscale)
{
    __shared__ __align__(16) unsigned char lds[4 * 64 * 128];
    const int lid = blockIdx.y * 16 + blockIdx.x;
    const int xcd = lid & 7, slot = lid >> 3;        // slot in [0,80)
    const int y = xcd * 5 + (slot >> 4);
    const int x = slot & 15;
    if (y < 8) {
        bgemm2<64, 64, 3, 0>(apk, wpk, ipb, qp, 1024, qscale,
                             y * 64, x * 64, lds);
    } else if (y < 24) {
        bgemm2<64, 64, 3, 1>(apk + 512L * 2048, wpk + 1024L * 2048, ipb + 1024, sbuf, 1024, 1.f,
                             (y - 8) * 64, x * 64, lds);
    } else {
        bgemm2<64, 64, 2, 0>(apk + 1536L * 2048, wpk + 2048L * 2048, ipb + 2048, vp, 1024, 1.f,
                             (y - 24) * 64, x * 64, lds);
    }
}

// ---- out projection, 32x64 tiles, 2-term, XCD-swizzled. grid 256
__global__ __launch_bounds__(256) void outprojb_kernel(
    const unsigned short* __restrict__ apk2, const unsigned short* __restrict__ wpk,
    const float* __restrict__ opb, float* __restrict__ out)
{
    __shared__ __align__(16) unsigned char lds[(2 * 32 + 64) * 128];
    const int lid = blockIdx.x;
    const int xcd = lid & 7, slot = lid >> 3;        // slot in [0,32)
    const int y = xcd * 2 + (slot >> 4);             // 16 y tiles of 32 rows
    const int x = slot & 15;
    bgemm2<32, 64, 2, 0>(apk2, wpk + 3072L * 2048, opb, out, 1024, 1.f,
                         y * 32, x * 64, lds);
}

// ============ fused attention, 4-way q split, 2 blocks/CU. grid 128, XCD-swizzled ====
// LDS: QH 8K | QL 8K | KH 16K (Vt overlay) | KL 16K | PH 16K | RED 512B | INV 128B
#define F_QH 0
#define F_QL 8192
#define F_KH 16384
#define F_KL 32768
#define F_PH 49152
#define F_RED 65536
#define F_INV 66048

__global__ __launch_bounds__(256, 2) void fused_attn_kernel(
    const float* __restrict__ qp, const float* __restrict__ sbuf,
    const float* __restrict__ vp, const int* __restrict__ indices,
    unsigned short* __restrict__ apk2)
{
    __shared__ __align__(16) unsigned char lds[66176];
    __shared__ int onode[256];
    const int lid = blockIdx.x;
    const int xcd = lid & 7, slot = lid >> 3;
    const int bh = xcd * 4 + (slot >> 2), qq = slot & 3;
    const int b = bh >> 3, h = bh & 7;
    const int t = threadIdx.x, lane = t & 63, wave = t >> 6;
    const int wm = wave >> 1, wn = wave & 1;
    float* red = (float*)(lds + F_RED);
    float* inv = (float*)(lds + F_INV);

    if (t < TK) {
        const int r0 = indices[(b * TK + t) * 2 + 0];
        const int c0 = indices[(b * TK + t) * 2 + 1];
        onode[t] = t + 2 * (c0 - r0) + 1;
    } else if (t < 256) {
        onode[t] = 255;
    }

    {
        const int c4 = t & 31, r8 = t >> 5;
        #pragma unroll
        for (int rr = 0; rr < 4; ++rr) {
            const int row = r8 + rr * 8;
            const int tq = qq * 32 + row;
            float4 f = *(const float4*)(qp + (long)(tq * 4 + b) * 1024 + h * 128 + c4 * 4);
            const unsigned short h0 = f2bf(f.x), h1 = f2bf(f.y), h2 = f2bf(f.z), h3 = f2bf(f.w);
            short4v hv, lv;
            hv[0] = (short)h0; hv[1] = (short)h1; hv[2] = (short)h2; hv[3] = (short)h3;
            lv[0] = (short)f2bf(f.x - bfbits2f(h0));
            lv[1] = (short)f2bf(f.y - bfbits2f(h1));
            lv[2] = (short)f2bf(f.z - bfbits2f(h2));
            lv[3] = (short)f2bf(f.w - bfbits2f(h3));
            const int byte = row * 256 + ((((c4 >> 1) ^ (row & 15)) << 4) | ((c4 & 1) << 3));
            *(short4v*)(lds + F_QH + byte) = hv;
            *(short4v*)(lds + F_QL + byte) = lv;
        }
    }

    f32x4 acc[4][2];
    #pragma unroll
    for (int nb = 0; nb < 4; ++nb)
        #pragma unroll
        for (int j = 0; j < 2; ++j)
            #pragma unroll
            for (int e = 0; e < 4; ++e) acc[nb][j][e] = 0.f;

    #pragma unroll
    for (int nb = 0; nb < 4; ++nb) {
        __syncthreads();
        {
            const int c4 = t & 31, r8 = t >> 5;
            const float* sb = sbuf + (long)b * 256 * 1024 + h * 128 + c4 * 4;
            #pragma unroll
            for (int rr = 0; rr < 8; ++rr) {
                const int nl = r8 + rr * 8;
                const int node = nb * 64 + nl;
                float4 f0 = *(const float4*)(sb + (long)node * 1024);
                float4 f1 = *(const float4*)(sb + (long)onode[node] * 1024);
                float4 f = make_float4(f0.x - f1.x, f0.y - f1.y, f0.z - f1.z, f0.w - f1.w);
                const unsigned short h0 = f2bf(f.x), h1 = f2bf(f.y), h2 = f2bf(f.z), h3 = f2bf(f.w);
                short4v hv, lv;
                hv[0] = (short)h0; hv[1] = (short)h1; hv[2] = (short)h2; hv[3] = (short)h3;
                lv[0] = (short)f2bf(f.x - bfbits2f(h0));
                lv[1] = (short)f2bf(f.y - bfbits2f(h1));
                lv[2] = (short)f2bf(f.z - bfbits2f(h2));
                lv[3] = (short)f2bf(f.w - bfbits2f(h3));
                const int byte = nl * 256 + ((((c4 >> 1) ^ (nl & 15)) << 4) | ((c4 & 1) << 3));
                *(short4v*)(lds + F_KH + byte) = hv;
                *(short4v*)(lds + F_KL + byte) = lv;
            }
        }
        __syncthreads();
        #pragma unroll
        for (int ks = 0; ks < 4; ++ks) {
            short8 ah, al, bh_[2], bl[2];
            {
                const int row = wm * 16 + (lane & 15);
                const int byte = row * 256 + (((ks * 4 + (lane >> 4)) ^ (row & 15)) << 4);
                ah = *(const short8*)(lds + F_QH + byte);
                al = *(const short8*)(lds + F_QL + byte);
            }
            #pragma unroll
            for (int fn = 0; fn < 2; ++fn) {
                const int row = wn * 32 + fn * 16 + (lane & 15);
                const int byte = row * 256 + (((ks * 4 + (lane >> 4)) ^ (row & 15)) << 4);
                bh_[fn] = *(const short8*)(lds + F_KH + byte);
                bl[fn] = *(const short8*)(lds + F_KL + byte);
            }
            #pragma unroll
            for (int fn = 0; fn < 2; ++fn) {
                acc[nb][fn] = __builtin_amdgcn_mfma_f32_16x16x32_bf16(ah, bh_[fn], acc[nb][fn], 0, 0, 0);
                acc[nb][fn] = __builtin_amdgcn_mfma_f32_16x16x32_bf16(al, bh_[fn], acc[nb][fn], 0, 0, 0);
                acc[nb][fn] = __builtin_amdgcn_mfma_f32_16x16x32_bf16(ah, bl[fn], acc[nb][fn], 0, 0, 0);
            }
        }
    }

    float pmax[4] = {-1e30f, -1e30f, -1e30f, -1e30f};
    #pragma unroll
    for (int nb = 0; nb < 4; ++nb)
        #pragma unroll
        for (int fn = 0; fn < 2; ++fn)
            #pragma unroll
            for (int i = 0; i < 4; ++i) {
                const int col = nb * 64 + wn * 32 + fn * 16 + (lane & 15);
                const float s = (col < TK) ? acc[nb][fn][i] : -1e30f;
                pmax[i] = fmaxf(pmax[i], s);
            }
    #pragma unroll
    for (int off = 1; off < 16; off <<= 1)
        #pragma unroll
        for (int i = 0; i < 4; ++i) pmax[i] = fmaxf(pmax[i], __shfl_xor(pmax[i], off));
    if ((lane & 15) == 0) {
        #pragma unroll
        for (int i = 0; i < 4; ++i) {
            const int row = wm * 16 + ((lane >> 4) << 2) + i;
            red[wn * 32 + row] = pmax[i];
        }
    }
    __syncthreads();
    float rm[4];
    #pragma unroll
    for (int i = 0; i < 4; ++i) {
        const int row = wm * 16 + ((lane >> 4) << 2) + i;
        rm[i] = fmaxf(red[row], red[32 + row]);
    }
    float psum[4] = {0.f, 0.f, 0.f, 0.f};
    #pragma unroll
    for (int nb = 0; nb < 4; ++nb)
        #pragma unroll
        for (int fn = 0; fn < 2; ++fn)
            #pragma unroll
            for (int i = 0; i < 4; ++i) {
                const int col = nb * 64 + wn * 32 + fn * 16 + (lane & 15);
                const int row = wm * 16 + ((lane >> 4) << 2) + i;
                float p = 0.f;
                if (col < TK) p = __expf(acc[nb][fn][i] - rm[i]);
                psum[i] += p;
                const unsigned short hp = f2bf(p);
                const int u = ((col >> 3) ^ ((row & 15) << 1));
                const int byte = row * 512 + (u << 4) + (col & 7) * 2;
                *(unsigned short*)(lds + F_PH + byte) = hp;
            }
    #pragma unroll
    for (int off = 1; off < 16; off <<= 1)
        #pragma unroll
        for (int i = 0; i < 4; ++i) psum[i] += __shfl_xor(psum[i], off);
    if ((lane & 15) == 0) {
        #pragma unroll
        for (int i = 0; i < 4; ++i) {
            const int row = wm * 16 + ((lane >> 4) << 2) + i;
            red[64 + wn * 32 + row] = psum[i];
        }
    }
    __syncthreads();
    if (wn == 0 && (lane & 15) == 0) {
        #pragma unroll
        for (int i = 0; i < 4; ++i) {
            const int row = wm * 16 + ((lane >> 4) << 2) + i;
            inv[row] = 1.f / (red[64 + row] + red[96 + row]);
        }
    }

    f32x4 accO[4];
    #pragma unroll
    for (int fn = 0; fn < 4; ++fn)
        #pragma unroll
        for (int e = 0; e < 4; ++e) accO[fn][e] = 0.f;

    #pragma unroll
    for (int nb = 0; nb < 4; ++nb) {
        __syncthreads();
        {
            const int c4 = t & 31, r8 = t >> 5;
            #pragma unroll
            for (int rr = 0; rr < 8; ++rr) {
                const int nl = r8 + rr * 8;
                const int node = nb * 64 + nl;
                float4 f = make_float4(0.f, 0.f, 0.f, 0.f);
                if (node < TK) f = *(const float4*)(vp + (long)(node * 4 + b) * 1024 + h * 128 + c4 * 4);
                const float fa[4] = {f.x, f.y, f.z, f.w};
                #pragma unroll
                for (int j = 0; j < 4; ++j) {
                    const int d = c4 * 4 + j;
                    const int byte = d * 128 + ((((nl >> 3) ^ (d & 7)) << 4) | ((nl & 7) << 1));
                    *(unsigned short*)(lds + F_KH + byte) = f2bf(fa[j]);
                }
            }
        }
        __syncthreads();
        #pragma unroll
        for (int ks = 0; ks < 2; ++ks) {
            short8 pa, vb[4];
            {
                const int row = wm * 16 + (lane & 15);
                const int u = (nb * 8 + ks * 4 + (lane >> 4)) ^ ((row & 15) << 1);
                const int byte = row * 512 + (u << 4);
                pa = *(const short8*)(lds + F_PH + byte);
            }
            #pragma unroll
            for (int fn = 0; fn < 4; ++fn) {
                const int d = wn * 64 + fn * 16 + (lane & 15);
                const int u = (ks * 4 + (lane >> 4)) ^ (d & 7);
                const int byte = d * 128 + (u << 4);
                vb[fn] = *(const short8*)(lds + F_KH + byte);
            }
            #pragma unroll
            for (int fn = 0; fn < 4; ++fn)
                accO[fn] = __builtin_amdgcn_mfma_f32_16x16x32_bf16(pa, vb[fn], accO[fn], 0, 0, 0);
        }
    }

    __syncthreads();
    #pragma unroll
    for (int i = 0; i < 4; ++i) {
        const int row = wm * 16 + ((lane >> 4) << 2) + i;
        const float iv = inv[row];
        const int arow = (qq * 32 + row) * 4 + b;
        #pragma unroll
        for (int fn = 0; fn < 4; ++fn) {
            const int col = h * 128 + wn * 64 + fn * 16 + (lane & 15);
            const float val = accO[fn][i] * iv;
            const unsigned short hv = f2bf(val);
            const unsigned short lv = f2bf(val - bfbits2f(hv));
            apk2[(long)arow * 2048 + col] = hv;
            apk2[(long)arow * 2048 + 1024 + col] = lv;
        }
    }
}

extern "C" void kernel_launch(void* const* d_in, const int* in_sizes, int n_in,
                              void* d_out, int out_size, void* d_ws, size_t ws_size,
                              hipStream_t stream) {
    const float* query   = (const float*)d_in[0];
    const float* key_t   = (const float*)d_in[1];
    const float* value   = (const float*)d_in[2];
    const int*   indices = (const int*)d_in[3];
    const float* ipw     = (const float*)d_in[4];
    const float* ipb     = (const float*)d_in[5];
    const float* opw     = (const float*)d_in[6];
    const float* opb     = (const float*)d_in[7];
    float* out = (float*)d_out;

    float* ws = (float*)d_ws;
    float* vp   = ws;                        // [1024][1024]
    float* qp   = vp + 1048576;              // [512][1024]
    float* sbuf = qp + 524288;               // [4][256][1024] projected suffix sums
    float* ssp  = sbuf + 1048576;            // [4][256][1024] raw key suffix sums
    unsigned short* apk  = (unsigned short*)(ssp + 1048576);   // [2560][2048]
    unsigned short* wpk  = apk + 2560L * 2048;                 // [4096][2048]
    unsigned short* apk2 = apk;              // overlay (apk dead after qkvb)

    const float qscale = 0.08838834764831843f;  // 128^-0.5

    rawsuffix_kernel<<<dim3(32, 4), 256, 0, stream>>>(key_t, ssp);

    pack_all<<<dim3(2048), 256, 0, stream>>>(query, ssp, value, ipw, opw, apk, wpk);

    qkvb_kernel<<<dim3(16, 40), 256, 0, stream>>>(apk, wpk, ipb, qp, sbuf, vp, qscale);

    fused_attn_kernel<<<dim3(128), 256, 0, stream>>>(qp, sbuf, vp, indices, apk2);

    outprojb_kernel<<<dim3(256), 256, 0, stream>>>(apk2, wpk, opb, out);
}

// Round 12
// 87.545 us; speedup vs baseline: 1.3730x; 1.0094x over previous
//
#include <hip/hip_runtime.h>
#include <math.h>

#define EMBED 1024
#define NHEAD 8
#define HDIM 128
#define TK 255
#define BATCH 4
#define LQ 128
#define BH 32

typedef __attribute__((ext_vector_type(4))) float f32x4;
typedef __attribute__((ext_vector_type(8))) short short8;
typedef __attribute__((ext_vector_type(4))) short short4v;

static __device__ __forceinline__ unsigned short f2bf(float f) {
    unsigned u = __float_as_uint(f);
    u += 0x7FFFu + ((u >> 16) & 1u);
    return (unsigned short)(u >> 16);
}
static __device__ __forceinline__ float bfbits2f(unsigned short s) {
    return __uint_as_float(((unsigned)s) << 16);
}

// ============ rawsuffix: ssp[b][n][e] = sum_{m=n..254} key_t[m][b][e]; ssp[b][255]=0 ====
__global__ __launch_bounds__(256) void rawsuffix_kernel(
    const float* __restrict__ key_t, float* __restrict__ ssp)
{
    const int b = blockIdx.y;
    const int cl = threadIdx.x & 31;
    const int e = blockIdx.x * 32 + cl;
    const int seg = threadIdx.x >> 5;       // 0..7
    __shared__ float tot[8][33];
    float acc = 0.f;
    const int nhi = seg * 32 + 31;
    #pragma unroll 8
    for (int i = 0; i < 32; ++i) {
        const int n = nhi - i;
        float v = 0.f;
        if (n < TK) v = key_t[(long)(n * 4 + b) * 1024 + e];
        acc += v;
        ssp[((long)b * 256 + n) * 1024 + e] = acc;
    }
    tot[seg][cl] = acc;
    __syncthreads();
    float add = 0.f;
    #pragma unroll
    for (int s = 0; s < 8; ++s) if (s > seg) add += tot[s][cl];
    if (seg < 7) {
        #pragma unroll 8
        for (int i = 0; i < 32; ++i) {
            const int n = seg * 32 + i;
            ssp[((long)b * 256 + n) * 1024 + e] += add;
        }
    }
}

// ============ pack: fp32 -> bf16 [hi | lo]. A: query(512) | ssp(1024) | value(1020+pad).
// W: ipw(3072) | opw(1024); lo-plane skipped for rows >= 2048 (2-term GEMMs never read it).
__global__ __launch_bounds__(256) void pack_all(
    const float* __restrict__ query, const float* __restrict__ ssp,
    const float* __restrict__ value, const float* __restrict__ ipw,
    const float* __restrict__ opw,
    unsigned short* __restrict__ apk, unsigned short* __restrict__ wpk)
{
    const int APKC = 2560 * 256;
    const int TOT = APKC + 4096 * 256;
    for (int idx = blockIdx.x * 256 + threadIdx.x; idx < TOT; idx += gridDim.x * 256) {
        const bool isA = idx < APKC;
        const int rel = isA ? idx : idx - APKC;
        const int row = rel >> 8, c4 = rel & 255;
        const float* src = nullptr; long srow = 0;
        unsigned short* dst;
        bool wlo = true;
        if (isA) {
            dst = apk + (long)row * 2048;
            if (row < 512) { src = query; srow = row; }
            else if (row < 1536) { src = ssp; srow = row - 512; }
            else { if (row - 1536 < 1020) { src = value; srow = row - 1536; } }
        } else {
            dst = wpk + (long)row * 2048;
            if (row < 3072) { src = ipw; srow = row; }
            else { src = opw; srow = row - 3072; }
            wlo = (row < 2048);
        }
        float4 f = make_float4(0.f, 0.f, 0.f, 0.f);
        if (src) f = *(const float4*)(src + srow * 1024 + c4 * 4);
        const unsigned short h0 = f2bf(f.x), h1 = f2bf(f.y), h2 = f2bf(f.z), h3 = f2bf(f.w);
        short4v hv;
        hv[0] = (short)h0; hv[1] = (short)h1; hv[2] = (short)h2; hv[3] = (short)h3;
        *(short4v*)(dst + c4 * 4) = hv;
        if (wlo) {
            short4v lv;
            lv[0] = (short)f2bf(f.x - bfbits2f(h0));
            lv[1] = (short)f2bf(f.y - bfbits2f(h1));
            lv[2] = (short)f2bf(f.z - bfbits2f(h2));
            lv[3] = (short)f2bf(f.w - bfbits2f(h3));
            *(short4v*)(dst + 1024 + c4 * 4) = lv;
        }
    }
}

// ============ bgemm2: all-plane BK=64 staging, TERMS MFMAs per fragment pair ============
// EPI 0: C = (acc + bias)*scale.  EPI 1: C = acc + (255 - (m&255)) * bias[n].
template<int BM, int BN, int TERMS, int EPI>
__device__ __forceinline__ void bgemm2(
    const unsigned short* __restrict__ A,
    const unsigned short* __restrict__ B,
    const float* __restrict__ bias,
    float* __restrict__ C, long ldc, float scale,
    int m0, int n0, unsigned char* lds)
{
    constexpr int AH = 0;
    constexpr int AL = BM * 128;
    constexpr int BHo = 2 * BM * 128;
    constexpr int BLo = BHo + BN * 128;
    constexpr int FM2 = BM / 32, FN2 = BN / 32;
    constexpr int CA = BM / 32;
    constexpr int CB = BN / 32;
    const int t = threadIdx.x, lane = t & 63, wave = t >> 6;
    const int wm = wave >> 1, wn = wave & 1;

    f32x4 acc[FM2][FN2];
    #pragma unroll
    for (int i = 0; i < FM2; ++i)
        #pragma unroll
        for (int j = 0; j < FN2; ++j)
            #pragma unroll
            for (int e = 0; e < 4; ++e) acc[i][j][e] = 0.f;

    const int srow_a = t >> 3, su = t & 7;
    short8 rah[CA], ral[CA], rbh[CB], rbl[CB];

    #pragma unroll
    for (int c = 0; c < CA; ++c) {
        const long base = (long)(m0 + c * 32 + srow_a) * 2048 + su * 8;
        rah[c] = *(const short8*)(A + base);
        ral[c] = *(const short8*)(A + base + 1024);
    }
    #pragma unroll
    for (int c = 0; c < CB; ++c) {
        const long base = (long)(n0 + c * 32 + srow_a) * 2048 + su * 8;
        rbh[c] = *(const short8*)(B + base);
        if (TERMS == 3) rbl[c] = *(const short8*)(B + base + 1024);
    }

    for (int kt = 0; kt < 16; ++kt) {
        #pragma unroll
        for (int c = 0; c < CA; ++c) {
            const int row = c * 32 + srow_a;
            const int byte = row * 128 + ((su ^ (row & 7)) << 4);
            *(short8*)(lds + AH + byte) = rah[c];
            *(short8*)(lds + AL + byte) = ral[c];
        }
        #pragma unroll
        for (int c = 0; c < CB; ++c) {
            const int row = c * 32 + srow_a;
            const int byte = row * 128 + ((su ^ (row & 7)) << 4);
            *(short8*)(lds + BHo + byte) = rbh[c];
            if (TERMS == 3) *(short8*)(lds + BLo + byte) = rbl[c];
        }
        __syncthreads();
        if (kt + 1 < 16) {
            const int off = (kt + 1) * 64;
            #pragma unroll
            for (int c = 0; c < CA; ++c) {
                const long base = (long)(m0 + c * 32 + srow_a) * 2048 + off + su * 8;
                rah[c] = *(const short8*)(A + base);
                ral[c] = *(const short8*)(A + base + 1024);
            }
            #pragma unroll
            for (int c = 0; c < CB; ++c) {
                const long base = (long)(n0 + c * 32 + srow_a) * 2048 + off + su * 8;
                rbh[c] = *(const short8*)(B + base);
                if (TERMS == 3) rbl[c] = *(const short8*)(B + base + 1024);
            }
        }
        #pragma unroll
        for (int ks = 0; ks < 2; ++ks) {
            short8 afh[FM2], afl[FM2], bgh[FN2], bgl[FN2];
            #pragma unroll
            for (int fm = 0; fm < FM2; ++fm) {
                const int row = wm * (BM / 2) + fm * 16 + (lane & 15);
                const int byte = row * 128 + (((ks * 4 + (lane >> 4)) ^ (row & 7)) << 4);
                afh[fm] = *(const short8*)(lds + AH + byte);
                afl[fm] = *(const short8*)(lds + AL + byte);
            }
            #pragma unroll
            for (int fn = 0; fn < FN2; ++fn) {
                const int row = wn * (BN / 2) + fn * 16 + (lane & 15);
                const int byte = row * 128 + (((ks * 4 + (lane >> 4)) ^ (row & 7)) << 4);
                bgh[fn] = *(const short8*)(lds + BHo + byte);
                if (TERMS == 3) bgl[fn] = *(const short8*)(lds + BLo + byte);
            }
            #pragma unroll
            for (int fm = 0; fm < FM2; ++fm)
                #pragma unroll
                for (int fn = 0; fn < FN2; ++fn) {
                    acc[fm][fn] = __builtin_amdgcn_mfma_f32_16x16x32_bf16(afh[fm], bgh[fn], acc[fm][fn], 0, 0, 0);
                    acc[fm][fn] = __builtin_amdgcn_mfma_f32_16x16x32_bf16(afl[fm], bgh[fn], acc[fm][fn], 0, 0, 0);
                    if (TERMS == 3)
                        acc[fm][fn] = __builtin_amdgcn_mfma_f32_16x16x32_bf16(afh[fm], bgl[fn], acc[fm][fn], 0, 0, 0);
                }
        }
        __syncthreads();
    }

    #pragma unroll
    for (int fm = 0; fm < FM2; ++fm)
        #pragma unroll
        for (int i = 0; i < 4; ++i) {
            const int m = m0 + wm * (BM / 2) + fm * 16 + ((lane >> 4) << 2) + i;
            #pragma unroll
            for (int fn = 0; fn < FN2; ++fn) {
                const int n = n0 + wn * (BN / 2) + fn * 16 + (lane & 15);
                float v = acc[fm][fn][i];
                if (EPI == 0) {
                    if (bias) v += bias[n];
                    v *= scale;
                } else {
                    v += (float)(255 - (m & 255)) * bias[n];
                }
                C[(long)m * ldc + n] = v;
            }
        }
}

// ---- fused q/k(suffix)/v projections, 64x64 tiles, XCD-swizzled. grid (16, 40)
// y<8: Q (512 rows). y<24: suffix-K -> sbuf directly (1024 rows, rowcount bias). else V.
__global__ __launch_bounds__(256) void qkvb_kernel(
    const unsigned short* __restrict__ apk, const unsigned short* __restrict__ wpk,
    const float* __restrict__ ipb,
    float* __restrict__ qp, float* __restrict__ sbuf, float* __restrict__ vp, float qscale)
{
    __shared__ __align__(16) unsigned char lds[4 * 64 * 128];
    const int lid = blockIdx.y * 16 + blockIdx.x;
    const int xcd = lid & 7, slot = lid >> 3;        // slot in [0,80)
    const int y = xcd * 5 + (slot >> 4);
    const int x = slot & 15;
    if (y < 8) {
        bgemm2<64, 64, 3, 0>(apk, wpk, ipb, qp, 1024, qscale,
                             y * 64, x * 64, lds);
    } else if (y < 24) {
        bgemm2<64, 64, 3, 1>(apk + 512L * 2048, wpk + 1024L * 2048, ipb + 1024, sbuf, 1024, 1.f,
                             (y - 8) * 64, x * 64, lds);
    } else {
        bgemm2<64, 64, 2, 0>(apk + 1536L * 2048, wpk + 2048L * 2048, ipb + 2048, vp, 1024, 1.f,
                             (y - 24) * 64, x * 64, lds);
    }
}

// ---- out projection, 32x64 tiles, 2-term, XCD-swizzled. grid 256
__global__ __launch_bounds__(256) void outprojb_kernel(
    const unsigned short* __restrict__ apk2, const unsigned short* __restrict__ wpk,
    const float* __restrict__ opb, float* __restrict__ out)
{
    __shared__ __align__(16) unsigned char lds[(2 * 32 + 64) * 128];
    const int lid = blockIdx.x;
    const int xcd = lid & 7, slot = lid >> 3;        // slot in [0,32)
    const int y = xcd * 2 + (slot >> 4);             // 16 y tiles of 32 rows
    const int x = slot & 15;
    bgemm2<32, 64, 2, 0>(apk2, wpk + 3072L * 2048, opb, out, 1024, 1.f,
                         y * 32, x * 64, lds);
}

// ============ fused attention, 4-way q split, 2 blocks/CU. grid 128, XCD-swizzled ====
// LDS: QH 8K | QL 8K | KH 16K (Vt overlay) | KL 16K | PH 16K | RED 512B | INV 128B
#define F_QH 0
#define F_QL 8192
#define F_KH 16384
#define F_KL 32768
#define F_PH 49152
#define F_RED 65536
#define F_INV 66048

__global__ __launch_bounds__(256, 2) void fused_attn_kernel(
    const float* __restrict__ qp, const float* __restrict__ sbuf,
    const float* __restrict__ vp, const int* __restrict__ indices,
    unsigned short* __restrict__ apk2)
{
    __shared__ __align__(16) unsigned char lds[66176];
    __shared__ int onode[256];
    const int lid = blockIdx.x;
    const int xcd = lid & 7, slot = lid >> 3;
    const int bh = xcd * 4 + (slot >> 2), qq = slot & 3;
    const int b = bh >> 3, h = bh & 7;
    const int t = threadIdx.x, lane = t & 63, wave = t >> 6;
    const int wm = wave >> 1, wn = wave & 1;
    float* red = (float*)(lds + F_RED);
    float* inv = (float*)(lds + F_INV);

    if (t < TK) {
        const int r0 = indices[(b * TK + t) * 2 + 0];
        const int c0 = indices[(b * TK + t) * 2 + 1];
        onode[t] = t + 2 * (c0 - r0) + 1;
    } else if (t < 256) {
        onode[t] = 255;
    }

    {
        const int c4 = t & 31, r8 = t >> 5;
        #pragma unroll
        for (int rr = 0; rr < 4; ++rr) {
            const int row = r8 + rr * 8;
            const int tq = qq * 32 + row;
            float4 f = *(const float4*)(qp + (long)(tq * 4 + b) * 1024 + h * 128 + c4 * 4);
            const unsigned short h0 = f2bf(f.x), h1 = f2bf(f.y), h2 = f2bf(f.z), h3 = f2bf(f.w);
            short4v hv, lv;
            hv[0] = (short)h0; hv[1] = (short)h1; hv[2] = (short)h2; hv[3] = (short)h3;
            lv[0] = (short)f2bf(f.x - bfbits2f(h0));
            lv[1] = (short)f2bf(f.y - bfbits2f(h1));
            lv[2] = (short)f2bf(f.z - bfbits2f(h2));
            lv[3] = (short)f2bf(f.w - bfbits2f(h3));
            const int byte = row * 256 + ((((c4 >> 1) ^ (row & 15)) << 4) | ((c4 & 1) << 3));
            *(short4v*)(lds + F_QH + byte) = hv;
            *(short4v*)(lds + F_QL + byte) = lv;
        }
    }

    f32x4 acc[4][2];
    #pragma unroll
    for (int nb = 0; nb < 4; ++nb)
        #pragma unroll
        for (int j = 0; j < 2; ++j)
            #pragma unroll
            for (int e = 0; e < 4; ++e) acc[nb][j][e] = 0.f;

    #pragma unroll
    for (int nb = 0; nb < 4; ++nb) {
        __syncthreads();
        {
            const int c4 = t & 31, r8 = t >> 5;
            const float* sb = sbuf + (long)b * 256 * 1024 + h * 128 + c4 * 4;
            #pragma unroll
            for (int rr = 0; rr < 8; ++rr) {
                const int nl = r8 + rr * 8;
                const int node = nb * 64 + nl;
                float4 f0 = *(const float4*)(sb + (long)node * 1024);
                float4 f1 = *(const float4*)(sb + (long)onode[node] * 1024);
                float4 f = make_float4(f0.x - f1.x, f0.y - f1.y, f0.z - f1.z, f0.w - f1.w);
                const unsigned short h0 = f2bf(f.x), h1 = f2bf(f.y), h2 = f2bf(f.z), h3 = f2bf(f.w);
                short4v hv, lv;
                hv[0] = (short)h0; hv[1] = (short)h1; hv[2] = (short)h2; hv[3] = (short)h3;
                lv[0] = (short)f2bf(f.x - bfbits2f(h0));
                lv[1] = (short)f2bf(f.y - bfbits2f(h1));
                lv[2] = (short)f2bf(f.z - bfbits2f(h2));
                lv[3] = (short)f2bf(f.w - bfbits2f(h3));
                const int byte = nl * 256 + ((((c4 >> 1) ^ (nl & 15)) << 4) | ((c4 & 1) << 3));
                *(short4v*)(lds + F_KH + byte) = hv;
                *(short4v*)(lds + F_KL + byte) = lv;
            }
        }
        __syncthreads();
        #pragma unroll
        for (int ks = 0; ks < 4; ++ks) {
            short8 ah, al, bh_[2], bl[2];
            {
                const int row = wm * 16 + (lane & 15);
                const int byte = row * 256 + (((ks * 4 + (lane >> 4)) ^ (row & 15)) << 4);
                ah = *(const short8*)(lds + F_QH + byte);
                al = *(const short8*)(lds + F_QL + byte);
            }
            #pragma unroll
            for (int fn = 0; fn < 2; ++fn) {
                const int row = wn * 32 + fn * 16 + (lane & 15);
                const int byte = row * 256 + (((ks * 4 + (lane >> 4)) ^ (row & 15)) << 4);
                bh_[fn] = *(const short8*)(lds + F_KH + byte);
                bl[fn] = *(const short8*)(lds + F_KL + byte);
            }
            #pragma unroll
            for (int fn = 0; fn < 2; ++fn) {
                acc[nb][fn] = __builtin_amdgcn_mfma_f32_16x16x32_bf16(ah, bh_[fn], acc[nb][fn], 0, 0, 0);
                acc[nb][fn] = __builtin_amdgcn_mfma_f32_16x16x32_bf16(al, bh_[fn], acc[nb][fn], 0, 0, 0);
                acc[nb][fn] = __builtin_amdgcn_mfma_f32_16x16x32_bf16(ah, bl[fn], acc[nb][fn], 0, 0, 0);
            }
        }
    }

    float pmax[4] = {-1e30f, -1e30f, -1e30f, -1e30f};
    #pragma unroll
    for (int nb = 0; nb < 4; ++nb)
        #pragma unroll
        for (int fn = 0; fn < 2; ++fn)
            #pragma unroll
            for (int i = 0; i < 4; ++i) {
                const int col = nb * 64 + wn * 32 + fn * 16 + (lane & 15);
                const float s = (col < TK) ? acc[nb][fn][i] : -1e30f;
                pmax[i] = fmaxf(pmax[i], s);
            }
    #pragma unroll
    for (int off = 1; off < 16; off <<= 1)
        #pragma unroll
        for (int i = 0; i < 4; ++i) pmax[i] = fmaxf(pmax[i], __shfl_xor(pmax[i], off));
    if ((lane & 15) == 0) {
        #pragma unroll
        for (int i = 0; i < 4; ++i) {
            const int row = wm * 16 + ((lane >> 4) << 2) + i;
            red[wn * 32 + row] = pmax[i];
        }
    }
    __syncthreads();
    float rm[4];
    #pragma unroll
    for (int i = 0; i < 4; ++i) {
        const int row = wm * 16 + ((lane >> 4) << 2) + i;
        rm[i] = fmaxf(red[row], red[32 + row]);
    }
    float psum[4] = {0.f, 0.f, 0.f, 0.f};
    #pragma unroll
    for (int nb = 0; nb < 4; ++nb)
        #pragma unroll
        for (int fn = 0; fn < 2; ++fn)
            #pragma unroll
            for (int i = 0; i < 4; ++i) {
                const int col = nb * 64 + wn * 32 + fn * 16 + (lane & 15);
                const int row = wm * 16 + ((lane >> 4) << 2) + i;
                float p = 0.f;
                if (col < TK) p = __expf(acc[nb][fn][i] - rm[i]);
                psum[i] += p;
                const unsigned short hp = f2bf(p);
                const int u = ((col >> 3) ^ ((row & 15) << 1));
                const int byte = row * 512 + (u << 4) + (col & 7) * 2;
                *(unsigned short*)(lds + F_PH + byte) = hp;
            }
    #pragma unroll
    for (int off = 1; off < 16; off <<= 1)
        #pragma unroll
        for (int i = 0; i < 4; ++i) psum[i] += __shfl_xor(psum[i], off);
    if ((lane & 15) == 0) {
        #pragma unroll
        for (int i = 0; i < 4; ++i) {
            const int row = wm * 16 + ((lane >> 4) << 2) + i;
            red[64 + wn * 32 + row] = psum[i];
        }
    }
    __syncthreads();
    if (wn == 0 && (lane & 15) == 0) {
        #pragma unroll
        for (int i = 0; i < 4; ++i) {
            const int row = wm * 16 + ((lane >> 4) << 2) + i;
            inv[row] = 1.f / (red[64 + row] + red[96 + row]);
        }
    }

    f32x4 accO[4];
    #pragma unroll
    for (int fn = 0; fn < 4; ++fn)
        #pragma unroll
        for (int e = 0; e < 4; ++e) accO[fn][e] = 0.f;

    #pragma unroll
    for (int nb = 0; nb < 4; ++nb) {
        __syncthreads();
        {
            const int c4 = t & 31, r8 = t >> 5;
            #pragma unroll
            for (int rr = 0; rr < 8; ++rr) {
                const int nl = r8 + rr * 8;
                const int node = nb * 64 + nl;
                float4 f = make_float4(0.f, 0.f, 0.f, 0.f);
                if (node < TK) f = *(const float4*)(vp + (long)(node * 4 + b) * 1024 + h * 128 + c4 * 4);
                const float fa[4] = {f.x, f.y, f.z, f.w};
                #pragma unroll
                for (int j = 0; j < 4; ++j) {
                    const int d = c4 * 4 + j;
                    const int byte = d * 128 + ((((nl >> 3) ^ (d & 7)) << 4) | ((nl & 7) << 1));
                    *(unsigned short*)(lds + F_KH + byte) = f2bf(fa[j]);
                }
            }
        }
        __syncthreads();
        #pragma unroll
        for (int ks = 0; ks < 2; ++ks) {
            short8 pa, vb[4];
            {
                const int row = wm * 16 + (lane & 15);
                const int u = (nb * 8 + ks * 4 + (lane >> 4)) ^ ((row & 15) << 1);
                const int byte = row * 512 + (u << 4);
                pa = *(const short8*)(lds + F_PH + byte);
            }
            #pragma unroll
            for (int fn = 0; fn < 4; ++fn) {
                const int d = wn * 64 + fn * 16 + (lane & 15);
                const int u = (ks * 4 + (lane >> 4)) ^ (d & 7);
                const int byte = d * 128 + (u << 4);
                vb[fn] = *(const short8*)(lds + F_KH + byte);
            }
            #pragma unroll
            for (int fn = 0; fn < 4; ++fn)
                accO[fn] = __builtin_amdgcn_mfma_f32_16x16x32_bf16(pa, vb[fn], accO[fn], 0, 0, 0);
        }
    }

    __syncthreads();
    #pragma unroll
    for (int i = 0; i < 4; ++i) {
        const int row = wm * 16 + ((lane >> 4) << 2) + i;
        const float iv = inv[row];
        const int arow = (qq * 32 + row) * 4 + b;
        #pragma unroll
        for (int fn = 0; fn < 4; ++fn) {
            const int col = h * 128 + wn * 64 + fn * 16 + (lane & 15);
            const float val = accO[fn][i] * iv;
            const unsigned short hv = f2bf(val);
            const unsigned short lv = f2bf(val - bfbits2f(hv));
            apk2[(long)arow * 2048 + col] = hv;
            apk2[(long)arow * 2048 + 1024 + col] = lv;
        }
    }
}

extern "C" void kernel_launch(void* const* d_in, const int* in_sizes, int n_in,
                              void* d_out, int out_size, void* d_ws, size_t ws_size,
                              hipStream_t stream) {
    const float* query   = (const float*)d_in[0];
    const float* key_t   = (const float*)d_in[1];
    const float* value   = (const float*)d_in[2];
    const int*   indices = (const int*)d_in[3];
    const float* ipw     = (const float*)d_in[4];
    const float* ipb     = (const float*)d_in[5];
    const float* opw     = (const float*)d_in[6];
    const float* opb     = (const float*)d_in[7];
    float* out = (float*)d_out;

    float* ws = (float*)d_ws;
    float* vp   = ws;                        // [1024][1024]
    float* qp   = vp + 1048576;              // [512][1024]
    float* sbuf = qp + 524288;               // [4][256][1024] projected suffix sums
    float* ssp  = sbuf + 1048576;            // [4][256][1024] raw key suffix sums
    unsigned short* apk  = (unsigned short*)(ssp + 1048576);   // [2560][2048]
    unsigned short* wpk  = apk + 2560L * 2048;                 // [4096][2048]
    unsigned short* apk2 = apk;              // overlay (apk dead after qkvb)

    const float qscale = 0.08838834764831843f;  // 128^-0.5

    rawsuffix_kernel<<<dim3(32, 4), 256, 0, stream>>>(key_t, ssp);

    pack_all<<<dim3(2048), 256, 0, stream>>>(query, ssp, value, ipw, opw, apk, wpk);

    qkvb_kernel<<<dim3(16, 40), 256, 0, stream>>>(apk, wpk, ipb, qp, sbuf, vp, qscale);

    fused_attn_kernel<<<dim3(128), 256, 0, stream>>>(qp, sbuf, vp, indices, apk2);

    outprojb_kernel<<<dim3(256), 256, 0, stream>>>(apk2, wpk, opb, out);
}

// Round 13
// 70.185 us; speedup vs baseline: 1.7126x; 1.2473x over previous
//
#include <hip/hip_runtime.h>
#include <math.h>

#define EMBED 1024
#define NHEAD 8
#define HDIM 128
#define TK 255
#define BATCH 4
#define LQ 128
#define BH 32

typedef __attribute__((ext_vector_type(4))) float f32x4;
typedef __attribute__((ext_vector_type(8))) short short8;
typedef __attribute__((ext_vector_type(4))) short short4v;

static __device__ __forceinline__ unsigned short f2bf(float f) {
    unsigned u = __float_as_uint(f);
    u += 0x7FFFu + ((u >> 16) & 1u);
    return (unsigned short)(u >> 16);
}
static __device__ __forceinline__ float bfbits2f(unsigned short s) {
    return __uint_as_float(((unsigned)s) << 16);
}

// ============ prep: (blocks 0..127) suffix-scan keys -> packed apk rows 512..1535
//              (blocks 128..2175) pack query/value/weights -> apk / wpk
__global__ __launch_bounds__(256) void prep_kernel(
    const float* __restrict__ query, const float* __restrict__ key_t,
    const float* __restrict__ value, const float* __restrict__ ipw,
    const float* __restrict__ opw,
    unsigned short* __restrict__ apk, unsigned short* __restrict__ wpk)
{
    const int blk = blockIdx.x;
    const int t = threadIdx.x;
    if (blk < 128) {
        // suffix scan: S[b][n][e] = sum_{m=n..254} key[m][b][e]; emit bf16 hi/lo
        const int b = blk >> 5, eg = blk & 31;
        const int cl = t & 31, seg = t >> 5;        // 8 segments of 32 nodes
        const int e = eg * 32 + cl;
        __shared__ float tot[8][33];
        float vals[32];
        float acc = 0.f;
        const int nhi = seg * 32 + 31;
        #pragma unroll
        for (int i = 0; i < 32; ++i) {
            const int n = nhi - i;
            float v = 0.f;
            if (n < TK) v = key_t[(long)(n * 4 + b) * 1024 + e];
            acc += v;
            vals[i] = acc;
        }
        tot[seg][cl] = acc;
        __syncthreads();
        float add = 0.f;
        #pragma unroll
        for (int s = 0; s < 8; ++s) if (s > seg) add += tot[s][cl];
        #pragma unroll
        for (int i = 0; i < 32; ++i) {
            const int n = nhi - i;
            const float f = vals[i] + add;
            const unsigned short hv = f2bf(f);
            const unsigned short lv = f2bf(f - bfbits2f(hv));
            unsigned short* dst = apk + (long)(512 + b * 256 + n) * 2048 + e;
            dst[0] = hv;
            dst[1024] = lv;
        }
    } else {
        // pack: A-part rows: query(512) then value(1024 incl pad); W: ipw(3072)+opw(1024)
        const int APKC = 1536 * 256;
        const int TOT = APKC + 4096 * 256;
        for (int idx = (blk - 128) * 256 + t; idx < TOT; idx += 2048 * 256) {
            const bool isA = idx < APKC;
            const int rel = isA ? idx : idx - APKC;
            const int row = rel >> 8, c4 = rel & 255;
            const float* src = nullptr; long srow = 0;
            unsigned short* dst;
            bool wlo = true;
            if (isA) {
                if (row < 512) { src = query; srow = row; dst = apk + (long)row * 2048; }
                else {
                    const int vr = row - 512;
                    dst = apk + (long)(1536 + vr) * 2048;
                    if (vr < 1020) { src = value; srow = vr; }
                }
            } else {
                dst = wpk + (long)row * 2048;
                if (row < 3072) { src = ipw; srow = row; }
                else { src = opw; srow = row - 3072; }
                wlo = (row < 2048);   // V/out weights are 2-term: B-lo never read
            }
            float4 f = make_float4(0.f, 0.f, 0.f, 0.f);
            if (src) f = *(const float4*)(src + srow * 1024 + c4 * 4);
            const unsigned short h0 = f2bf(f.x), h1 = f2bf(f.y), h2 = f2bf(f.z), h3 = f2bf(f.w);
            short4v hv;
            hv[0] = (short)h0; hv[1] = (short)h1; hv[2] = (short)h2; hv[3] = (short)h3;
            *(short4v*)(dst + c4 * 4) = hv;
            if (wlo) {
                short4v lv;
                lv[0] = (short)f2bf(f.x - bfbits2f(h0));
                lv[1] = (short)f2bf(f.y - bfbits2f(h1));
                lv[2] = (short)f2bf(f.z - bfbits2f(h2));
                lv[3] = (short)f2bf(f.w - bfbits2f(h3));
                *(short4v*)(dst + 1024 + c4 * 4) = lv;
            }
        }
    }
}

// ============ bgemm2: all-plane BK=64 staging, TERMS MFMAs per fragment pair ============
// EPI 0: fp32 C = (acc + bias)*scale.   EPI 1: fp32 C = acc + (255-(m&255))*bias.
// EPI 2: packed bf16 hi/lo (ld 2048), (acc+bias)*scale.  EPI 3: bf16 hi only (ld 1024), acc+bias.
template<int BM, int BN, int TERMS, int EPI>
__device__ __forceinline__ void bgemm2(
    const unsigned short* __restrict__ A,
    const unsigned short* __restrict__ B,
    const float* __restrict__ bias,
    void* __restrict__ Cv, long ldc, float scale,
    int m0, int n0, unsigned char* lds)
{
    constexpr int AH = 0;
    constexpr int AL = BM * 128;
    constexpr int BHo = 2 * BM * 128;
    constexpr int BLo = BHo + BN * 128;
    constexpr int FM2 = BM / 32, FN2 = BN / 32;
    constexpr int CA = BM / 32;
    constexpr int CB = BN / 32;
    const int t = threadIdx.x, lane = t & 63, wave = t >> 6;
    const int wm = wave >> 1, wn = wave & 1;

    f32x4 acc[FM2][FN2];
    #pragma unroll
    for (int i = 0; i < FM2; ++i)
        #pragma unroll
        for (int j = 0; j < FN2; ++j)
            #pragma unroll
            for (int e = 0; e < 4; ++e) acc[i][j][e] = 0.f;

    const int srow_a = t >> 3, su = t & 7;
    short8 rah[CA], ral[CA], rbh[CB], rbl[CB];

    #pragma unroll
    for (int c = 0; c < CA; ++c) {
        const long base = (long)(m0 + c * 32 + srow_a) * 2048 + su * 8;
        rah[c] = *(const short8*)(A + base);
        ral[c] = *(const short8*)(A + base + 1024);
    }
    #pragma unroll
    for (int c = 0; c < CB; ++c) {
        const long base = (long)(n0 + c * 32 + srow_a) * 2048 + su * 8;
        rbh[c] = *(const short8*)(B + base);
        if (TERMS == 3) rbl[c] = *(const short8*)(B + base + 1024);
    }

    for (int kt = 0; kt < 16; ++kt) {
        #pragma unroll
        for (int c = 0; c < CA; ++c) {
            const int row = c * 32 + srow_a;
            const int byte = row * 128 + ((su ^ (row & 7)) << 4);
            *(short8*)(lds + AH + byte) = rah[c];
            *(short8*)(lds + AL + byte) = ral[c];
        }
        #pragma unroll
        for (int c = 0; c < CB; ++c) {
            const int row = c * 32 + srow_a;
            const int byte = row * 128 + ((su ^ (row & 7)) << 4);
            *(short8*)(lds + BHo + byte) = rbh[c];
            if (TERMS == 3) *(short8*)(lds + BLo + byte) = rbl[c];
        }
        __syncthreads();
        if (kt + 1 < 16) {
            const int off = (kt + 1) * 64;
            #pragma unroll
            for (int c = 0; c < CA; ++c) {
                const long base = (long)(m0 + c * 32 + srow_a) * 2048 + off + su * 8;
                rah[c] = *(const short8*)(A + base);
                ral[c] = *(const short8*)(A + base + 1024);
            }
            #pragma unroll
            for (int c = 0; c < CB; ++c) {
                const long base = (long)(n0 + c * 32 + srow_a) * 2048 + off + su * 8;
                rbh[c] = *(const short8*)(B + base);
                if (TERMS == 3) rbl[c] = *(const short8*)(B + base + 1024);
            }
        }
        #pragma unroll
        for (int ks = 0; ks < 2; ++ks) {
            short8 afh[FM2], afl[FM2], bgh[FN2], bgl[FN2];
            #pragma unroll
            for (int fm = 0; fm < FM2; ++fm) {
                const int row = wm * (BM / 2) + fm * 16 + (lane & 15);
                const int byte = row * 128 + (((ks * 4 + (lane >> 4)) ^ (row & 7)) << 4);
                afh[fm] = *(const short8*)(lds + AH + byte);
                afl[fm] = *(const short8*)(lds + AL + byte);
            }
            #pragma unroll
            for (int fn = 0; fn < FN2; ++fn) {
                const int row = wn * (BN / 2) + fn * 16 + (lane & 15);
                const int byte = row * 128 + (((ks * 4 + (lane >> 4)) ^ (row & 7)) << 4);
                bgh[fn] = *(const short8*)(lds + BHo + byte);
                if (TERMS == 3) bgl[fn] = *(const short8*)(lds + BLo + byte);
            }
            #pragma unroll
            for (int fm = 0; fm < FM2; ++fm)
                #pragma unroll
                for (int fn = 0; fn < FN2; ++fn) {
                    acc[fm][fn] = __builtin_amdgcn_mfma_f32_16x16x32_bf16(afh[fm], bgh[fn], acc[fm][fn], 0, 0, 0);
                    acc[fm][fn] = __builtin_amdgcn_mfma_f32_16x16x32_bf16(afl[fm], bgh[fn], acc[fm][fn], 0, 0, 0);
                    if (TERMS == 3)
                        acc[fm][fn] = __builtin_amdgcn_mfma_f32_16x16x32_bf16(afh[fm], bgl[fn], acc[fm][fn], 0, 0, 0);
                }
        }
        __syncthreads();
    }

    #pragma unroll
    for (int fm = 0; fm < FM2; ++fm)
        #pragma unroll
        for (int i = 0; i < 4; ++i) {
            const int m = m0 + wm * (BM / 2) + fm * 16 + ((lane >> 4) << 2) + i;
            #pragma unroll
            for (int fn = 0; fn < FN2; ++fn) {
                const int n = n0 + wn * (BN / 2) + fn * 16 + (lane & 15);
                float v = acc[fm][fn][i];
                if (EPI == 0) {
                    float* C = (float*)Cv;
                    if (bias) v += bias[n];
                    C[(long)m * ldc + n] = v * scale;
                } else if (EPI == 1) {
                    float* C = (float*)Cv;
                    v += (float)(255 - (m & 255)) * bias[n];
                    C[(long)m * ldc + n] = v;
                } else if (EPI == 2) {
                    unsigned short* C = (unsigned short*)Cv;
                    const float val = (v + bias[n]) * scale;
                    const unsigned short hv = f2bf(val);
                    const unsigned short lv = f2bf(val - bfbits2f(hv));
                    C[(long)m * 2048 + n] = hv;
                    C[(long)m * 2048 + 1024 + n] = lv;
                } else {
                    unsigned short* C = (unsigned short*)Cv;
                    const float val = v + bias[n];
                    C[(long)m * 1024 + n] = f2bf(val);
                }
            }
        }
}

// ---- fused q/k(suffix)/v projections, 64x64 tiles, XCD-swizzled. grid (16, 40)
__global__ __launch_bounds__(256) void qkvb_kernel(
    const unsigned short* __restrict__ apk, const unsigned short* __restrict__ wpk,
    const float* __restrict__ ipb,
    unsigned short* __restrict__ qpk, float* __restrict__ sbuf,
    unsigned short* __restrict__ vpk, float qscale)
{
    __shared__ __align__(16) unsigned char lds[4 * 64 * 128];
    const int lid = blockIdx.y * 16 + blockIdx.x;
    const int xcd = lid & 7, slot = lid >> 3;        // slot in [0,80)
    const int y = xcd * 5 + (slot >> 4);
    const int x = slot & 15;
    if (y < 8) {
        bgemm2<64, 64, 3, 2>(apk, wpk, ipb, qpk, 2048, qscale,
                             y * 64, x * 64, lds);
    } else if (y < 24) {
        bgemm2<64, 64, 3, 1>(apk + 512L * 2048, wpk + 1024L * 2048, ipb + 1024, sbuf, 1024, 1.f,
                             (y - 8) * 64, x * 64, lds);
    } else {
        bgemm2<64, 64, 2, 3>(apk + 1536L * 2048, wpk + 2048L * 2048, ipb + 2048, vpk, 1024, 1.f,
                             (y - 24) * 64, x * 64, lds);
    }
}

// ---- out projection, 32x64 tiles, 2-term, XCD-swizzled. grid 256
__global__ __launch_bounds__(256) void outprojb_kernel(
    const unsigned short* __restrict__ apk2, const unsigned short* __restrict__ wpk,
    const float* __restrict__ opb, float* __restrict__ out)
{
    __shared__ __align__(16) unsigned char lds[(2 * 32 + 64) * 128];
    const int lid = blockIdx.x;
    const int xcd = lid & 7, slot = lid >> 3;        // slot in [0,32)
    const int y = xcd * 2 + (slot >> 4);
    const int x = slot & 15;
    bgemm2<32, 64, 2, 0>(apk2, wpk + 3072L * 2048, opb, out, 1024, 1.f,
                         y * 32, x * 64, lds);
}

// ============ fused attention, 4-way q split, 2 blocks/CU. grid 128, XCD-swizzled ====
// LDS: QH 8K | QL 8K | KH 16K (Vt overlay) | KL 16K | PH 16K | RED 512B | INV 128B
#define F_QH 0
#define F_QL 8192
#define F_KH 16384
#define F_KL 32768
#define F_PH 49152
#define F_RED 65536
#define F_INV 66048

__global__ __launch_bounds__(256, 2) void fused_attn_kernel(
    const unsigned short* __restrict__ qpk, const float* __restrict__ sbuf,
    const unsigned short* __restrict__ vpk, const int* __restrict__ indices,
    unsigned short* __restrict__ apk2)
{
    __shared__ __align__(16) unsigned char lds[66176];
    __shared__ int onode[256];
    const int lid = blockIdx.x;
    const int xcd = lid & 7, slot = lid >> 3;
    const int bh = xcd * 4 + (slot >> 2), qq = slot & 3;
    const int b = bh >> 3, h = bh & 7;
    const int t = threadIdx.x, lane = t & 63, wave = t >> 6;
    const int wm = wave >> 1, wn = wave & 1;
    float* red = (float*)(lds + F_RED);
    float* inv = (float*)(lds + F_INV);

    if (t < TK) {
        const int r0 = indices[(b * TK + t) * 2 + 0];
        const int c0 = indices[(b * TK + t) * 2 + 1];
        onode[t] = t + 2 * (c0 - r0) + 1;
    } else if (t < 256) {
        onode[t] = 255;
    }

    // ---- stage Q: straight short8 copy from packed qpk (FIX: + h*128 head offset)
    {
        #pragma unroll
        for (int rr = 0; rr < 4; ++rr) {
            const int chunk = rr * 256 + t;        // 1024 = 32 rows x 2 planes x 16 units
            const int row = chunk >> 5;
            const int rem = chunk & 31;
            const int plane = rem >> 4, u = rem & 15;
            const int tq = qq * 32 + row;
            short8 v = *(const short8*)(qpk + (long)(tq * 4 + b) * 2048 + plane * 1024 + h * 128 + u * 8);
            const int byte = row * 256 + ((u ^ (row & 15)) << 4);
            *(short8*)(lds + (plane ? F_QL : F_QH) + byte) = v;
        }
    }

    f32x4 acc[4][2];
    #pragma unroll
    for (int nb = 0; nb < 4; ++nb)
        #pragma unroll
        for (int j = 0; j < 2; ++j)
            #pragma unroll
            for (int e = 0; e < 4; ++e) acc[nb][j][e] = 0.f;

    #pragma unroll
    for (int nb = 0; nb < 4; ++nb) {
        __syncthreads();
        {   // stage k~: S[node] - S[onode], split hi/lo
            const int c4 = t & 31, r8 = t >> 5;
            const float* sb = sbuf + (long)b * 256 * 1024 + h * 128 + c4 * 4;
            #pragma unroll
            for (int rr = 0; rr < 8; ++rr) {
                const int nl = r8 + rr * 8;
                const int node = nb * 64 + nl;
                float4 f0 = *(const float4*)(sb + (long)node * 1024);
                float4 f1 = *(const float4*)(sb + (long)onode[node] * 1024);
                float4 f = make_float4(f0.x - f1.x, f0.y - f1.y, f0.z - f1.z, f0.w - f1.w);
                const unsigned short h0 = f2bf(f.x), h1 = f2bf(f.y), h2 = f2bf(f.z), h3 = f2bf(f.w);
                short4v hv, lv;
                hv[0] = (short)h0; hv[1] = (short)h1; hv[2] = (short)h2; hv[3] = (short)h3;
                lv[0] = (short)f2bf(f.x - bfbits2f(h0));
                lv[1] = (short)f2bf(f.y - bfbits2f(h1));
                lv[2] = (short)f2bf(f.z - bfbits2f(h2));
                lv[3] = (short)f2bf(f.w - bfbits2f(h3));
                const int byte = nl * 256 + ((((c4 >> 1) ^ (nl & 15)) << 4) | ((c4 & 1) << 3));
                *(short4v*)(lds + F_KH + byte) = hv;
                *(short4v*)(lds + F_KL + byte) = lv;
            }
        }
        __syncthreads();
        #pragma unroll
        for (int ks = 0; ks < 4; ++ks) {
            short8 ah, al, bh_[2], bl[2];
            {
                const int row = wm * 16 + (lane & 15);
                const int byte = row * 256 + (((ks * 4 + (lane >> 4)) ^ (row & 15)) << 4);
                ah = *(const short8*)(lds + F_QH + byte);
                al = *(const short8*)(lds + F_QL + byte);
            }
            #pragma unroll
            for (int fn = 0; fn < 2; ++fn) {
                const int row = wn * 32 + fn * 16 + (lane & 15);
                const int byte = row * 256 + (((ks * 4 + (lane >> 4)) ^ (row & 15)) << 4);
                bh_[fn] = *(const short8*)(lds + F_KH + byte);
                bl[fn] = *(const short8*)(lds + F_KL + byte);
            }
            #pragma unroll
            for (int fn = 0; fn < 2; ++fn) {
                acc[nb][fn] = __builtin_amdgcn_mfma_f32_16x16x32_bf16(ah, bh_[fn], acc[nb][fn], 0, 0, 0);
                acc[nb][fn] = __builtin_amdgcn_mfma_f32_16x16x32_bf16(al, bh_[fn], acc[nb][fn], 0, 0, 0);
                acc[nb][fn] = __builtin_amdgcn_mfma_f32_16x16x32_bf16(ah, bl[fn], acc[nb][fn], 0, 0, 0);
            }
        }
    }

    float pmax[4] = {-1e30f, -1e30f, -1e30f, -1e30f};
    #pragma unroll
    for (int nb = 0; nb < 4; ++nb)
        #pragma unroll
        for (int fn = 0; fn < 2; ++fn)
            #pragma unroll
            for (int i = 0; i < 4; ++i) {
                const int col = nb * 64 + wn * 32 + fn * 16 + (lane & 15);
                const float s = (col < TK) ? acc[nb][fn][i] : -1e30f;
                pmax[i] = fmaxf(pmax[i], s);
            }
    #pragma unroll
    for (int off = 1; off < 16; off <<= 1)
        #pragma unroll
        for (int i = 0; i < 4; ++i) pmax[i] = fmaxf(pmax[i], __shfl_xor(pmax[i], off));
    if ((lane & 15) == 0) {
        #pragma unroll
        for (int i = 0; i < 4; ++i) {
            const int row = wm * 16 + ((lane >> 4) << 2) + i;
            red[wn * 32 + row] = pmax[i];
        }
    }
    __syncthreads();
    float rm[4];
    #pragma unroll
    for (int i = 0; i < 4; ++i) {
        const int row = wm * 16 + ((lane >> 4) << 2) + i;
        rm[i] = fmaxf(red[row], red[32 + row]);
    }
    float psum[4] = {0.f, 0.f, 0.f, 0.f};
    #pragma unroll
    for (int nb = 0; nb < 4; ++nb)
        #pragma unroll
        for (int fn = 0; fn < 2; ++fn)
            #pragma unroll
            for (int i = 0; i < 4; ++i) {
                const int col = nb * 64 + wn * 32 + fn * 16 + (lane & 15);
                const int row = wm * 16 + ((lane >> 4) << 2) + i;
                float p = 0.f;
                if (col < TK) p = __expf(acc[nb][fn][i] - rm[i]);
                psum[i] += p;
                const unsigned short hp = f2bf(p);
                const int u = ((col >> 3) ^ ((row & 15) << 1));
                const int byte = row * 512 + (u << 4) + (col & 7) * 2;
                *(unsigned short*)(lds + F_PH + byte) = hp;
            }
    #pragma unroll
    for (int off = 1; off < 16; off <<= 1)
        #pragma unroll
        for (int i = 0; i < 4; ++i) psum[i] += __shfl_xor(psum[i], off);
    if ((lane & 15) == 0) {
        #pragma unroll
        for (int i = 0; i < 4; ++i) {
            const int row = wm * 16 + ((lane >> 4) << 2) + i;
            red[64 + wn * 32 + row] = psum[i];
        }
    }
    __syncthreads();
    if (wn == 0 && (lane & 15) == 0) {
        #pragma unroll
        for (int i = 0; i < 4; ++i) {
            const int row = wm * 16 + ((lane >> 4) << 2) + i;
            inv[row] = 1.f / (red[64 + row] + red[96 + row]);
        }
    }

    f32x4 accO[4];
    #pragma unroll
    for (int fn = 0; fn < 4; ++fn)
        #pragma unroll
        for (int e = 0; e < 4; ++e) accO[fn][e] = 0.f;

    #pragma unroll
    for (int nb = 0; nb < 4; ++nb) {
        __syncthreads();
        {   // transpose-stage V (bf16 direct from vpk): Vt[d][n] in KH region
            const int c8 = t & 15, r16 = t >> 4;
            #pragma unroll
            for (int rr = 0; rr < 4; ++rr) {
                const int nl = r16 + rr * 16;
                const int node = nb * 64 + nl;
                short8 v = {0, 0, 0, 0, 0, 0, 0, 0};
                if (node < TK) v = *(const short8*)(vpk + (long)(node * 4 + b) * 1024 + h * 128 + c8 * 8);
                #pragma unroll
                for (int j = 0; j < 8; ++j) {
                    const int d = c8 * 8 + j;
                    const int byte = d * 128 + ((((nl >> 3) ^ (d & 7)) << 4) | ((nl & 7) << 1));
                    *(unsigned short*)(lds + F_KH + byte) = (unsigned short)v[j];
                }
            }
        }
        __syncthreads();
        #pragma unroll
        for (int ks = 0; ks < 2; ++ks) {
            short8 pa, vb[4];
            {
                const int row = wm * 16 + (lane & 15);
                const int u = (nb * 8 + ks * 4 + (lane >> 4)) ^ ((row & 15) << 1);
                const int byte = row * 512 + (u << 4);
                pa = *(const short8*)(lds + F_PH + byte);
            }
            #pragma unroll
            for (int fn = 0; fn < 4; ++fn) {
                const int d = wn * 64 + fn * 16 + (lane & 15);
                const int u = (ks * 4 + (lane >> 4)) ^ (d & 7);
                const int byte = d * 128 + (u << 4);
                vb[fn] = *(const short8*)(lds + F_KH + byte);
            }
            #pragma unroll
            for (int fn = 0; fn < 4; ++fn)
                accO[fn] = __builtin_amdgcn_mfma_f32_16x16x32_bf16(pa, vb[fn], accO[fn], 0, 0, 0);
        }
    }

    __syncthreads();
    #pragma unroll
    for (int i = 0; i < 4; ++i) {
        const int row = wm * 16 + ((lane >> 4) << 2) + i;
        const float iv = inv[row];
        const int arow = (qq * 32 + row) * 4 + b;
        #pragma unroll
        for (int fn = 0; fn < 4; ++fn) {
            const int col = h * 128 + wn * 64 + fn * 16 + (lane & 15);
            const float val = accO[fn][i] * iv;
            const unsigned short hv = f2bf(val);
            const unsigned short lv = f2bf(val - bfbits2f(hv));
            apk2[(long)arow * 2048 + col] = hv;
            apk2[(long)arow * 2048 + 1024 + col] = lv;
        }
    }
}

extern "C" void kernel_launch(void* const* d_in, const int* in_sizes, int n_in,
                              void* d_out, int out_size, void* d_ws, size_t ws_size,
                              hipStream_t stream) {
    const float* query   = (const float*)d_in[0];
    const float* key_t   = (const float*)d_in[1];
    const float* value   = (const float*)d_in[2];
    const int*   indices = (const int*)d_in[3];
    const float* ipw     = (const float*)d_in[4];
    const float* ipb     = (const float*)d_in[5];
    const float* opw     = (const float*)d_in[6];
    const float* opb     = (const float*)d_in[7];
    float* out = (float*)d_out;

    float* ws = (float*)d_ws;
    float* sbuf = ws;                                          // [1024][1024] fp32 (4 MB)
    unsigned short* qpk = (unsigned short*)(sbuf + 1048576);   // [512][2048] bf16 hi/lo
    unsigned short* vpk = qpk + 512L * 2048;                   // [1024][1024] bf16 hi
    unsigned short* apk = vpk + 1024L * 1024;                  // [2560][2048]
    unsigned short* wpk = apk + 2560L * 2048;                  // [4096][2048]
    unsigned short* apk2 = apk;                                // overlay (apk dead after qkvb)

    const float qscale = 0.08838834764831843f;  // 128^-0.5

    prep_kernel<<<dim3(2176), 256, 0, stream>>>(query, key_t, value, ipw, opw, apk, wpk);

    qkvb_kernel<<<dim3(16, 40), 256, 0, stream>>>(apk, wpk, ipb, qpk, sbuf, vpk, qscale);

    fused_attn_kernel<<<dim3(128), 256, 0, stream>>>(qpk, sbuf, vpk, indices, apk2);

    outprojb_kernel<<<dim3(256), 256, 0, stream>>>(apk2, wpk, opb, out);
}

// Round 14
// 69.260 us; speedup vs baseline: 1.7355x; 1.0134x over previous
//
#include <hip/hip_runtime.h>
#include <math.h>

#define EMBED 1024
#define NHEAD 8
#define HDIM 128
#define TK 255
#define BATCH 4
#define LQ 128
#define BH 32

typedef __attribute__((ext_vector_type(4))) float f32x4;
typedef __attribute__((ext_vector_type(8))) short short8;
typedef __attribute__((ext_vector_type(4))) short short4v;

static __device__ __forceinline__ unsigned short f2bf(float f) {
    unsigned u = __float_as_uint(f);
    u += 0x7FFFu + ((u >> 16) & 1u);
    return (unsigned short)(u >> 16);
}
static __device__ __forceinline__ float bfbits2f(unsigned short s) {
    return __uint_as_float(((unsigned)s) << 16);
}

// ============ prep: (blocks 0..127) suffix-scan keys -> packed apk rows 512..1535
//              (blocks 128..2175) pack query/value/weights -> apk / wpk
__global__ __launch_bounds__(256) void prep_kernel(
    const float* __restrict__ query, const float* __restrict__ key_t,
    const float* __restrict__ value, const float* __restrict__ ipw,
    const float* __restrict__ opw,
    unsigned short* __restrict__ apk, unsigned short* __restrict__ wpk)
{
    const int blk = blockIdx.x;
    const int t = threadIdx.x;
    if (blk < 128) {
        const int b = blk >> 5, eg = blk & 31;
        const int cl = t & 31, seg = t >> 5;
        const int e = eg * 32 + cl;
        __shared__ float tot[8][33];
        float vals[32];
        float acc = 0.f;
        const int nhi = seg * 32 + 31;
        #pragma unroll
        for (int i = 0; i < 32; ++i) {
            const int n = nhi - i;
            float v = 0.f;
            if (n < TK) v = key_t[(long)(n * 4 + b) * 1024 + e];
            acc += v;
            vals[i] = acc;
        }
        tot[seg][cl] = acc;
        __syncthreads();
        float add = 0.f;
        #pragma unroll
        for (int s = 0; s < 8; ++s) if (s > seg) add += tot[s][cl];
        #pragma unroll
        for (int i = 0; i < 32; ++i) {
            const int n = nhi - i;
            const float f = vals[i] + add;
            const unsigned short hv = f2bf(f);
            const unsigned short lv = f2bf(f - bfbits2f(hv));
            unsigned short* dst = apk + (long)(512 + b * 256 + n) * 2048 + e;
            dst[0] = hv;
            dst[1024] = lv;
        }
    } else {
        const int APKC = 1536 * 256;
        const int TOT = APKC + 4096 * 256;
        for (int idx = (blk - 128) * 256 + t; idx < TOT; idx += 2048 * 256) {
            const bool isA = idx < APKC;
            const int rel = isA ? idx : idx - APKC;
            const int row = rel >> 8, c4 = rel & 255;
            const float* src = nullptr; long srow = 0;
            unsigned short* dst;
            bool wlo = true;
            if (isA) {
                if (row < 512) { src = query; srow = row; dst = apk + (long)row * 2048; }
                else {
                    const int vr = row - 512;
                    dst = apk + (long)(1536 + vr) * 2048;
                    if (vr < 1020) { src = value; srow = vr; }
                }
            } else {
                dst = wpk + (long)row * 2048;
                if (row < 3072) { src = ipw; srow = row; }
                else { src = opw; srow = row - 3072; }
                wlo = (row < 2048);
            }
            float4 f = make_float4(0.f, 0.f, 0.f, 0.f);
            if (src) f = *(const float4*)(src + srow * 1024 + c4 * 4);
            const unsigned short h0 = f2bf(f.x), h1 = f2bf(f.y), h2 = f2bf(f.z), h3 = f2bf(f.w);
            short4v hv;
            hv[0] = (short)h0; hv[1] = (short)h1; hv[2] = (short)h2; hv[3] = (short)h3;
            *(short4v*)(dst + c4 * 4) = hv;
            if (wlo) {
                short4v lv;
                lv[0] = (short)f2bf(f.x - bfbits2f(h0));
                lv[1] = (short)f2bf(f.y - bfbits2f(h1));
                lv[2] = (short)f2bf(f.z - bfbits2f(h2));
                lv[3] = (short)f2bf(f.w - bfbits2f(h3));
                *(short4v*)(dst + 1024 + c4 * 4) = lv;
            }
        }
    }
}

// ============ bgemm2: all-plane BK=64 staging, TERMS MFMAs per fragment pair ============
// EPI 0: fp32 C = (acc + bias)*scale.   EPI 1: fp32 C = acc + (255-(m&255))*bias.
// EPI 2: packed bf16 hi/lo (ld 2048), (acc+bias)*scale.  EPI 3: bf16 hi only (ld 1024), acc+bias.
template<int BM, int BN, int TERMS, int EPI>
__device__ __forceinline__ void bgemm2(
    const unsigned short* __restrict__ A,
    const unsigned short* __restrict__ B,
    const float* __restrict__ bias,
    void* __restrict__ Cv, long ldc, float scale,
    int m0, int n0, unsigned char* lds)
{
    constexpr int AH = 0;
    constexpr int AL = BM * 128;
    constexpr int BHo = 2 * BM * 128;
    constexpr int BLo = BHo + BN * 128;
    constexpr int FM2 = BM / 32, FN2 = BN / 32;
    constexpr int CA = BM / 32;
    constexpr int CB = BN / 32;
    const int t = threadIdx.x, lane = t & 63, wave = t >> 6;
    const int wm = wave >> 1, wn = wave & 1;

    f32x4 acc[FM2][FN2];
    #pragma unroll
    for (int i = 0; i < FM2; ++i)
        #pragma unroll
        for (int j = 0; j < FN2; ++j)
            #pragma unroll
            for (int e = 0; e < 4; ++e) acc[i][j][e] = 0.f;

    const int srow_a = t >> 3, su = t & 7;
    short8 rah[CA], ral[CA], rbh[CB], rbl[CB];

    #pragma unroll
    for (int c = 0; c < CA; ++c) {
        const long base = (long)(m0 + c * 32 + srow_a) * 2048 + su * 8;
        rah[c] = *(const short8*)(A + base);
        ral[c] = *(const short8*)(A + base + 1024);
    }
    #pragma unroll
    for (int c = 0; c < CB; ++c) {
        const long base = (long)(n0 + c * 32 + srow_a) * 2048 + su * 8;
        rbh[c] = *(const short8*)(B + base);
        if (TERMS == 3) rbl[c] = *(const short8*)(B + base + 1024);
    }

    for (int kt = 0; kt < 16; ++kt) {
        #pragma unroll
        for (int c = 0; c < CA; ++c) {
            const int row = c * 32 + srow_a;
            const int byte = row * 128 + ((su ^ (row & 7)) << 4);
            *(short8*)(lds + AH + byte) = rah[c];
            *(short8*)(lds + AL + byte) = ral[c];
        }
        #pragma unroll
        for (int c = 0; c < CB; ++c) {
            const int row = c * 32 + srow_a;
            const int byte = row * 128 + ((su ^ (row & 7)) << 4);
            *(short8*)(lds + BHo + byte) = rbh[c];
            if (TERMS == 3) *(short8*)(lds + BLo + byte) = rbl[c];
        }
        __syncthreads();
        if (kt + 1 < 16) {
            const int off = (kt + 1) * 64;
            #pragma unroll
            for (int c = 0; c < CA; ++c) {
                const long base = (long)(m0 + c * 32 + srow_a) * 2048 + off + su * 8;
                rah[c] = *(const short8*)(A + base);
                ral[c] = *(const short8*)(A + base + 1024);
            }
            #pragma unroll
            for (int c = 0; c < CB; ++c) {
                const long base = (long)(n0 + c * 32 + srow_a) * 2048 + off + su * 8;
                rbh[c] = *(const short8*)(B + base);
                if (TERMS == 3) rbl[c] = *(const short8*)(B + base + 1024);
            }
        }
        #pragma unroll
        for (int ks = 0; ks < 2; ++ks) {
            short8 afh[FM2], afl[FM2], bgh[FN2], bgl[FN2];
            #pragma unroll
            for (int fm = 0; fm < FM2; ++fm) {
                const int row = wm * (BM / 2) + fm * 16 + (lane & 15);
                const int byte = row * 128 + (((ks * 4 + (lane >> 4)) ^ (row & 7)) << 4);
                afh[fm] = *(const short8*)(lds + AH + byte);
                afl[fm] = *(const short8*)(lds + AL + byte);
            }
            #pragma unroll
            for (int fn = 0; fn < FN2; ++fn) {
                const int row = wn * (BN / 2) + fn * 16 + (lane & 15);
                const int byte = row * 128 + (((ks * 4 + (lane >> 4)) ^ (row & 7)) << 4);
                bgh[fn] = *(const short8*)(lds + BHo + byte);
                if (TERMS == 3) bgl[fn] = *(const short8*)(lds + BLo + byte);
            }
            #pragma unroll
            for (int fm = 0; fm < FM2; ++fm)
                #pragma unroll
                for (int fn = 0; fn < FN2; ++fn) {
                    acc[fm][fn] = __builtin_amdgcn_mfma_f32_16x16x32_bf16(afh[fm], bgh[fn], acc[fm][fn], 0, 0, 0);
                    acc[fm][fn] = __builtin_amdgcn_mfma_f32_16x16x32_bf16(afl[fm], bgh[fn], acc[fm][fn], 0, 0, 0);
                    if (TERMS == 3)
                        acc[fm][fn] = __builtin_amdgcn_mfma_f32_16x16x32_bf16(afh[fm], bgl[fn], acc[fm][fn], 0, 0, 0);
                }
        }
        __syncthreads();
    }

    #pragma unroll
    for (int fm = 0; fm < FM2; ++fm)
        #pragma unroll
        for (int i = 0; i < 4; ++i) {
            const int m = m0 + wm * (BM / 2) + fm * 16 + ((lane >> 4) << 2) + i;
            #pragma unroll
            for (int fn = 0; fn < FN2; ++fn) {
                const int n = n0 + wn * (BN / 2) + fn * 16 + (lane & 15);
                float v = acc[fm][fn][i];
                if (EPI == 0) {
                    float* C = (float*)Cv;
                    if (bias) v += bias[n];
                    C[(long)m * ldc + n] = v * scale;
                } else if (EPI == 1) {
                    float* C = (float*)Cv;
                    v += (float)(255 - (m & 255)) * bias[n];
                    C[(long)m * ldc + n] = v;
                } else if (EPI == 2) {
                    unsigned short* C = (unsigned short*)Cv;
                    const float val = (v + bias[n]) * scale;
                    const unsigned short hv = f2bf(val);
                    const unsigned short lv = f2bf(val - bfbits2f(hv));
                    C[(long)m * 2048 + n] = hv;
                    C[(long)m * 2048 + 1024 + n] = lv;
                } else {
                    unsigned short* C = (unsigned short*)Cv;
                    const float val = v + bias[n];
                    C[(long)m * 1024 + n] = f2bf(val);
                }
            }
        }
}

// ---- fused q/k(suffix)/v projections, 64x64 tiles, XCD-swizzled. grid (16, 40)
__global__ __launch_bounds__(256) void qkvb_kernel(
    const unsigned short* __restrict__ apk, const unsigned short* __restrict__ wpk,
    const float* __restrict__ ipb,
    unsigned short* __restrict__ qpk, float* __restrict__ sbuf,
    unsigned short* __restrict__ vpk, float qscale)
{
    __shared__ __align__(16) unsigned char lds[4 * 64 * 128];
    const int lid = blockIdx.y * 16 + blockIdx.x;
    const int xcd = lid & 7, slot = lid >> 3;        // slot in [0,80)
    const int y = xcd * 5 + (slot >> 4);
    const int x = slot & 15;
    if (y < 8) {
        bgemm2<64, 64, 3, 2>(apk, wpk, ipb, qpk, 2048, qscale,
                             y * 64, x * 64, lds);
    } else if (y < 24) {
        bgemm2<64, 64, 3, 1>(apk + 512L * 2048, wpk + 1024L * 2048, ipb + 1024, sbuf, 1024, 1.f,
                             (y - 8) * 64, x * 64, lds);
    } else {
        bgemm2<64, 64, 2, 3>(apk + 1536L * 2048, wpk + 2048L * 2048, ipb + 2048, vpk, 1024, 1.f,
                             (y - 24) * 64, x * 64, lds);
    }
}

// ---- out projection, 32x64 tiles, 2-term, XCD-swizzled. grid 256
__global__ __launch_bounds__(256) void outprojb_kernel(
    const unsigned short* __restrict__ apk2, const unsigned short* __restrict__ wpk,
    const float* __restrict__ opb, float* __restrict__ out)
{
    __shared__ __align__(16) unsigned char lds[(2 * 32 + 64) * 128];
    const int lid = blockIdx.x;
    const int xcd = lid & 7, slot = lid >> 3;        // slot in [0,32)
    const int y = xcd * 2 + (slot >> 4);
    const int x = slot & 15;
    bgemm2<32, 64, 2, 0>(apk2, wpk + 3072L * 2048, opb, out, 1024, 1.f,
                         y * 32, x * 64, lds);
}

// ============ fused attention, 8-way q split (16 q-rows/block), 2 blocks/CU. grid 256 ====
// Wave layout: 4 waves cover 4 column-chunks (wn in [0,4)); all waves share the 16 q-rows.
// LDS: QH 4K | QL 4K | KH 16K (Vt overlay) | KL 16K | PH 8K | RED 512B | INV 64B
#define F_QH 0
#define F_QL 4096
#define F_KH 8192
#define F_KL 24576
#define F_PH 40960
#define F_RED 49152
#define F_INV 49664

__global__ __launch_bounds__(256, 2) void fused_attn_kernel(
    const unsigned short* __restrict__ qpk, const float* __restrict__ sbuf,
    const unsigned short* __restrict__ vpk, const int* __restrict__ indices,
    unsigned short* __restrict__ apk2)
{
    __shared__ __align__(16) unsigned char lds[49728];
    __shared__ int onode[256];
    // XCD swizzle: 32 slots/xcd; bh = xcd*4 + slot>>3 (K/V/sbuf locality), qq8 = slot&7
    const int lid = blockIdx.x;
    const int xcd = lid & 7, slot = lid >> 3;        // slot in [0,32)
    const int bh = xcd * 4 + (slot >> 3), qq8 = slot & 7;
    const int b = bh >> 3, h = bh & 7;
    const int t = threadIdx.x, lane = t & 63, wn = t >> 6;  // wn = wave in [0,4)
    float* red = (float*)(lds + F_RED);   // [2 phase][4 wn][16 row]
    float* inv = (float*)(lds + F_INV);   // [16]

    if (t < TK) {
        const int r0 = indices[(b * TK + t) * 2 + 0];
        const int c0 = indices[(b * TK + t) * 2 + 1];
        onode[t] = t + 2 * (c0 - r0) + 1;
    } else if (t < 256) {
        onode[t] = 255;
    }

    // ---- stage Q (16 rows): straight short8 copy from packed qpk (incl. h*128 offset)
    {
        #pragma unroll
        for (int rr = 0; rr < 2; ++rr) {
            const int chunk = rr * 256 + t;        // 512 = 16 rows x 2 planes x 16 units
            const int row = chunk >> 5;
            const int rem = chunk & 31;
            const int plane = rem >> 4, u = rem & 15;
            const int tq = qq8 * 16 + row;
            short8 v = *(const short8*)(qpk + (long)(tq * 4 + b) * 2048 + plane * 1024 + h * 128 + u * 8);
            const int byte = row * 256 + ((u ^ (row & 15)) << 4);
            *(short8*)(lds + (plane ? F_QL : F_QH) + byte) = v;
        }
    }

    f32x4 acc[4];
    #pragma unroll
    for (int nb = 0; nb < 4; ++nb)
        #pragma unroll
        for (int e = 0; e < 4; ++e) acc[nb][e] = 0.f;

    #pragma unroll
    for (int nb = 0; nb < 4; ++nb) {
        __syncthreads();
        {   // stage k~: S[node] - S[onode], split hi/lo (64 nodes x 128 cols)
            const int c4 = t & 31, r8 = t >> 5;
            const float* sb = sbuf + (long)b * 256 * 1024 + h * 128 + c4 * 4;
            #pragma unroll
            for (int rr = 0; rr < 8; ++rr) {
                const int nl = r8 + rr * 8;
                const int node = nb * 64 + nl;
                float4 f0 = *(const float4*)(sb + (long)node * 1024);
                float4 f1 = *(const float4*)(sb + (long)onode[node] * 1024);
                float4 f = make_float4(f0.x - f1.x, f0.y - f1.y, f0.z - f1.z, f0.w - f1.w);
                const unsigned short h0 = f2bf(f.x), h1 = f2bf(f.y), h2 = f2bf(f.z), h3 = f2bf(f.w);
                short4v hv, lv;
                hv[0] = (short)h0; hv[1] = (short)h1; hv[2] = (short)h2; hv[3] = (short)h3;
                lv[0] = (short)f2bf(f.x - bfbits2f(h0));
                lv[1] = (short)f2bf(f.y - bfbits2f(h1));
                lv[2] = (short)f2bf(f.z - bfbits2f(h2));
                lv[3] = (short)f2bf(f.w - bfbits2f(h3));
                const int byte = nl * 256 + ((((c4 >> 1) ^ (nl & 15)) << 4) | ((c4 & 1) << 3));
                *(short4v*)(lds + F_KH + byte) = hv;
                *(short4v*)(lds + F_KL + byte) = lv;
            }
        }
        __syncthreads();
        #pragma unroll
        for (int ks = 0; ks < 4; ++ks) {
            short8 ah, al, bh_, bl;
            {
                const int row = lane & 15;
                const int byte = row * 256 + (((ks * 4 + (lane >> 4)) ^ (row & 15)) << 4);
                ah = *(const short8*)(lds + F_QH + byte);
                al = *(const short8*)(lds + F_QL + byte);
            }
            {
                const int rown = wn * 16 + (lane & 15);
                const int byte = rown * 256 + (((ks * 4 + (lane >> 4)) ^ (rown & 15)) << 4);
                bh_ = *(const short8*)(lds + F_KH + byte);
                bl = *(const short8*)(lds + F_KL + byte);
            }
            acc[nb] = __builtin_amdgcn_mfma_f32_16x16x32_bf16(ah, bh_, acc[nb], 0, 0, 0);
            acc[nb] = __builtin_amdgcn_mfma_f32_16x16x32_bf16(al, bh_, acc[nb], 0, 0, 0);
            acc[nb] = __builtin_amdgcn_mfma_f32_16x16x32_bf16(ah, bl, acc[nb], 0, 0, 0);
        }
    }

    // ---- softmax over 256 cols (col>=255 masked); rows 16, cols split 4 waves x 16 lanes
    float pmax[4] = {-1e30f, -1e30f, -1e30f, -1e30f};
    #pragma unroll
    for (int nb = 0; nb < 4; ++nb)
        #pragma unroll
        for (int i = 0; i < 4; ++i) {
            const int col = nb * 64 + wn * 16 + (lane & 15);
            const float s = (col < TK) ? acc[nb][i] : -1e30f;
            pmax[i] = fmaxf(pmax[i], s);
        }
    #pragma unroll
    for (int off = 1; off < 16; off <<= 1)
        #pragma unroll
        for (int i = 0; i < 4; ++i) pmax[i] = fmaxf(pmax[i], __shfl_xor(pmax[i], off));
    if ((lane & 15) == 0) {
        #pragma unroll
        for (int i = 0; i < 4; ++i) {
            const int row = ((lane >> 4) << 2) + i;
            red[wn * 16 + row] = pmax[i];
        }
    }
    __syncthreads();
    float rm[4];
    #pragma unroll
    for (int i = 0; i < 4; ++i) {
        const int row = ((lane >> 4) << 2) + i;
        rm[i] = fmaxf(fmaxf(red[row], red[16 + row]), fmaxf(red[32 + row], red[48 + row]));
    }
    float psum[4] = {0.f, 0.f, 0.f, 0.f};
    #pragma unroll
    for (int nb = 0; nb < 4; ++nb)
        #pragma unroll
        for (int i = 0; i < 4; ++i) {
            const int col = nb * 64 + wn * 16 + (lane & 15);
            const int row = ((lane >> 4) << 2) + i;
            float p = 0.f;
            if (col < TK) p = __expf(acc[nb][i] - rm[i]);
            psum[i] += p;
            const unsigned short hp = f2bf(p);
            const int u = ((col >> 3) ^ ((row & 15) << 1));
            const int byte = row * 512 + (u << 4) + (col & 7) * 2;
            *(unsigned short*)(lds + F_PH + byte) = hp;
        }
    #pragma unroll
    for (int off = 1; off < 16; off <<= 1)
        #pragma unroll
        for (int i = 0; i < 4; ++i) psum[i] += __shfl_xor(psum[i], off);
    if ((lane & 15) == 0) {
        #pragma unroll
        for (int i = 0; i < 4; ++i) {
            const int row = ((lane >> 4) << 2) + i;
            red[64 + wn * 16 + row] = psum[i];
        }
    }
    __syncthreads();
    if (wn == 0 && (lane & 15) == 0) {
        #pragma unroll
        for (int i = 0; i < 4; ++i) {
            const int row = ((lane >> 4) << 2) + i;
            inv[row] = 1.f / (red[64 + row] + red[80 + row] + red[96 + row] + red[112 + row]);
        }
    }

    // ---- PV: O = P . V, 1-term. Vt staged [128 d][64 n] in KH region; wave wn owns 32 d-cols.
    f32x4 accO[2];
    #pragma unroll
    for (int fn = 0; fn < 2; ++fn)
        #pragma unroll
        for (int e = 0; e < 4; ++e) accO[fn][e] = 0.f;

    #pragma unroll
    for (int nb = 0; nb < 4; ++nb) {
        __syncthreads();
        {   // transpose-stage V (bf16 direct from vpk): Vt[d][n]
            const int c8 = t & 15, r16 = t >> 4;
            #pragma unroll
            for (int rr = 0; rr < 4; ++rr) {
                const int nl = r16 + rr * 16;
                const int node = nb * 64 + nl;
                short8 v = {0, 0, 0, 0, 0, 0, 0, 0};
                if (node < TK) v = *(const short8*)(vpk + (long)(node * 4 + b) * 1024 + h * 128 + c8 * 8);
                #pragma unroll
                for (int j = 0; j < 8; ++j) {
                    const int d = c8 * 8 + j;
                    const int byte = d * 128 + ((((nl >> 3) ^ (d & 7)) << 4) | ((nl & 7) << 1));
                    *(unsigned short*)(lds + F_KH + byte) = (unsigned short)v[j];
                }
            }
        }
        __syncthreads();
        #pragma unroll
        for (int ks = 0; ks < 2; ++ks) {
            short8 pa, vb[2];
            {
                const int row = lane & 15;
                const int u = (nb * 8 + ks * 4 + (lane >> 4)) ^ ((row & 15) << 1);
                const int byte = row * 512 + (u << 4);
                pa = *(const short8*)(lds + F_PH + byte);
            }
            #pragma unroll
            for (int fn = 0; fn < 2; ++fn) {
                const int d = wn * 32 + fn * 16 + (lane & 15);
                const int u = (ks * 4 + (lane >> 4)) ^ (d & 7);
                const int byte = d * 128 + (u << 4);
                vb[fn] = *(const short8*)(lds + F_KH + byte);
            }
            #pragma unroll
            for (int fn = 0; fn < 2; ++fn)
                accO[fn] = __builtin_amdgcn_mfma_f32_16x16x32_bf16(pa, vb[fn], accO[fn], 0, 0, 0);
        }
    }

    // ---- epilogue: normalize + write packed bf16 [hi|lo] attn rows directly
    __syncthreads();
    #pragma unroll
    for (int i = 0; i < 4; ++i) {
        const int row = ((lane >> 4) << 2) + i;
        const float iv = inv[row];
        const int arow = (qq8 * 16 + row) * 4 + b;
        #pragma unroll
        for (int fn = 0; fn < 2; ++fn) {
            const int col = h * 128 + wn * 32 + fn * 16 + (lane & 15);
            const float val = accO[fn][i] * iv;
            const unsigned short hv = f2bf(val);
            const unsigned short lv = f2bf(val - bfbits2f(hv));
            apk2[(long)arow * 2048 + col] = hv;
            apk2[(long)arow * 2048 + 1024 + col] = lv;
        }
    }
}

extern "C" void kernel_launch(void* const* d_in, const int* in_sizes, int n_in,
                              void* d_out, int out_size, void* d_ws, size_t ws_size,
                              hipStream_t stream) {
    const float* query   = (const float*)d_in[0];
    const float* key_t   = (const float*)d_in[1];
    const float* value   = (const float*)d_in[2];
    const int*   indices = (const int*)d_in[3];
    const float* ipw     = (const float*)d_in[4];
    const float* ipb     = (const float*)d_in[5];
    const float* opw     = (const float*)d_in[6];
    const float* opb     = (const float*)d_in[7];
    float* out = (float*)d_out;

    float* ws = (float*)d_ws;
    float* sbuf = ws;                                          // [1024][1024] fp32 (4 MB)
    unsigned short* qpk = (unsigned short*)(sbuf + 1048576);   // [512][2048] bf16 hi/lo
    unsigned short* vpk = qpk + 512L * 2048;                   // [1024][1024] bf16 hi
    unsigned short* apk = vpk + 1024L * 1024;                  // [2560][2048]
    unsigned short* wpk = apk + 2560L * 2048;                  // [4096][2048]
    unsigned short* apk2 = apk;                                // overlay (apk dead after qkvb)

    const float qscale = 0.08838834764831843f;  // 128^-0.5

    prep_kernel<<<dim3(2176), 256, 0, stream>>>(query, key_t, value, ipw, opw, apk, wpk);

    qkvb_kernel<<<dim3(16, 40), 256, 0, stream>>>(apk, wpk, ipb, qpk, sbuf, vpk, qscale);

    fused_attn_kernel<<<dim3(256), 256, 0, stream>>>(qpk, sbuf, vpk, indices, apk2);

    outprojb_kernel<<<dim3(256), 256, 0, stream>>>(apk2, wpk, opb, out);
}